// Round 8
// baseline (872.822 us; speedup 1.0000x reference)
//
#include <hip/hip_runtime.h>
#include <math.h>

#define EPSV 1e-5f

typedef __attribute__((ext_vector_type(8))) short bf16x8;
typedef __attribute__((ext_vector_type(4))) float f32x4;

#define MFMA16(a, b, c) __builtin_amdgcn_mfma_f32_16x16x32_bf16(a, b, c, 0, 0, 0)

__device__ __forceinline__ short f2bf(float x) {
    unsigned u = __float_as_uint(x);
    unsigned r = (u + 0x7fffu + ((u >> 16) & 1u)) >> 16;
    return (short)r;
}
__device__ __forceinline__ float bf2f(short h) {
    return __uint_as_float(((unsigned)(unsigned short)h) << 16);
}
__device__ __forceinline__ void bsplit(float x, short& h, short& l) {
    h = f2bf(x);
    l = f2bf(x - bf2f(h));
}
__device__ __forceinline__ unsigned pack2(short a, short b) {
    return ((unsigned)(unsigned short)a) | (((unsigned)(unsigned short)b) << 16);
}

// ============ prep: weight packing + folds, roles by blockIdx (1027) =========
// B<256: P | [256,768): MT | [768,896): w2/w3 pack | [896,960): bb
// [960,1024): bc3 | [1024,1026): u | 1026: scales+w1+ub
__global__ __launch_bounds__(256) void prep_kernel(
    const float* __restrict__ w1, const float* __restrict__ b1,
    const float* __restrict__ w2, const float* __restrict__ w3,
    const float* __restrict__ mw1, const float* __restrict__ mw2,
    const float* __restrict__ w4, const float* __restrict__ b4,
    const float* __restrict__ sw2, const float* __restrict__ sb2,
    const float* __restrict__ mb2, const float* __restrict__ mb1,
    const float* __restrict__ b3,
    const float* __restrict__ g1, const float* __restrict__ be1,
    const float* __restrict__ m1, const float* __restrict__ v1,
    const float* __restrict__ g2, const float* __restrict__ be2,
    const float* __restrict__ m2, const float* __restrict__ v2,
    short* __restrict__ w1fh, short* __restrict__ w2fh, short* __restrict__ w3fh,
    short* __restrict__ Pfh, short* __restrict__ MTfh,
    float* __restrict__ sc1, float* __restrict__ shb1,
    float* __restrict__ sc2, float* __restrict__ sh2,
    float* __restrict__ u, float* __restrict__ bb, float* __restrict__ ub,
    float* __restrict__ bc3)
{
    __shared__ __align__(16) float shm[520];
    int B = blockIdx.x, t = threadIdx.x;
    int lane = t & 63, w = t >> 6;

    if (B < 256) {
        // P[c][o] = sum_d mw1[d][c]*w3[o][d] (hi only)
        float* col = shm;
        int c = B;
        col[t] = mw1[t * 256 + c];
        __syncthreads();
        int ks = c >> 5, qq = (c >> 3) & 3, jj = c & 7;
        for (int oo = t; oo < 512; oo += 256) {
            float acc = 0.f;
            for (int d = 0; d < 256; ++d) acc += col[d] * w3[oo * 512 + d];
            int ct = oo >> 4;
            size_t idx = ((size_t)(ct * 8 + ks) * 64 + qq * 16 + (oo & 15)) * 8 + jj;
            Pfh[idx] = f2bf(acc);
        }
        return;
    }

    if (B < 768) {
        // MT[k][n] = sum_o mw2[n][o]*w4[o][k] (hi only, frag-packed)
        float* row = shm;
        int qq = B - 256;
        row[t] = mw2[(size_t)qq * 512 + t];
        row[t + 256] = mw2[(size_t)qq * 512 + t + 256];
        __syncthreads();
        float a0 = 0.f, a1 = 0.f;
        for (int o = 0; o < 512; ++o) {
            float m = row[o];
            a0 += m * w4[o * 512 + t];
            a1 += m * w4[o * 512 + t + 256];
        }
        int ct = qq >> 4, nl = qq & 15;
        {
            int k = t;
            size_t i0 = (((size_t)(ct * 16 + (k >> 5))) << 9)
                      | ((((k >> 3) & 3) * 16 + nl) << 3) | (k & 7);
            MTfh[i0] = f2bf(a0);
        }
        {
            int k = t + 256;
            size_t i1 = (((size_t)(ct * 16 + (k >> 5))) << 9)
                      | ((((k >> 3) & 3) * 16 + nl) << 3) | (k & 7);
            MTfh[i1] = f2bf(a1);
        }
        return;
    }

    if (B < 896) {
        int tid = (B - 768) * 256 + t;   // 0..32767
        {
            int i = tid;
            int j = i & 7, ln = (i >> 3) & 63, rest = i >> 9;
            int ks = rest & 3, ct = rest >> 2;
            int o = ct * 16 + (ln & 15);
            int k = ks * 32 + (ln >> 4) * 8 + j;
            w2fh[i] = f2bf(w2[o * 128 + k]);
        }
        #pragma unroll
        for (int s = 0; s < 4; ++s) {
            int i = tid + s * 32768;
            int j = i & 7, ln = (i >> 3) & 63, rest = i >> 9;
            int ks = rest & 7, ct = rest >> 3;
            int o = ct * 16 + (ln & 15);
            int c = 256 + ks * 32 + (ln >> 4) * 8 + j;
            w3fh[i] = f2bf(w3[o * 512 + c]);
        }
        return;
    }

    if (B < 960) {
        float* b4s = shm;
        float* red = shm + 512;
        b4s[t] = b4[t];
        b4s[t + 256] = b4[t + 256];
        __syncthreads();
        int q0 = (B - 896) * 8;
        for (int i = 0; i < 8; ++i) {
            int q = q0 + i;
            float part = mw2[(size_t)q * 512 + t] * b4s[t]
                       + mw2[(size_t)q * 512 + 256 + t] * b4s[256 + t];
            #pragma unroll
            for (int off = 32; off > 0; off >>= 1) part += __shfl_down(part, off);
            if (lane == 0) red[w] = part;
            __syncthreads();
            if (t == 0) bb[q] = mb2[q] + red[0] + red[1] + red[2] + red[3];
            __syncthreads();
        }
        return;
    }

    if (B < 1024) {
        float* mb1s = shm;
        float* red = shm + 512;
        mb1s[t] = mb1[t];
        __syncthreads();
        int o0 = (B - 960) * 8;
        for (int i = 0; i < 8; ++i) {
            int o = o0 + i;
            float part = w3[(size_t)o * 512 + t] * mb1s[t];
            #pragma unroll
            for (int off = 32; off > 0; off >>= 1) part += __shfl_down(part, off);
            if (lane == 0) red[w] = part;
            __syncthreads();
            if (t == 0) bc3[o] = b3[o] + red[0] + red[1] + red[2] + red[3];
            __syncthreads();
        }
        return;
    }

    if (B < 1026) {
        int c = (B - 1024) * 256 + t;
        float acc = 0.f;
        for (int o = 0; o < 512; ++o) acc += sw2[o] * w4[o * 512 + c];
        u[c] = acc;
        return;
    }

    // scales + shb1 + w1 frags + ub
    if (t < 128) {
        float s = g1[t] * rsqrtf(v1[t] + EPSV);
        float sh = be1[t] - m1[t] * s;
        sc1[t] = s;
        shb1[t] = b1[t] * s + sh;
    }
    {
        float s = g2[t] * rsqrtf(v2[t] + EPSV);
        sc2[t] = s; sh2[t] = be2[t] - m2[t] * s;
        s = g2[t + 256] * rsqrtf(v2[t + 256] + EPSV);
        sc2[t + 256] = s; sh2[t + 256] = be2[t + 256] - m2[t + 256] * s;
    }
    #pragma unroll
    for (int s = 0; s < 16; ++s) {
        int i = t + s * 256;
        int j = i & 7, ln = (i >> 3) & 63, ct = i >> 9;
        int o = ct * 16 + (ln & 15);
        int k = (ln >> 4) * 8 + j;
        w1fh[i] = (k < 10) ? f2bf(w1[o * 10 + k]) : (short)0;
    }
    if (t < 64) {
        float part = 0.f;
        #pragma unroll
        for (int i = 0; i < 8; ++i) part += sw2[t * 8 + i] * b4[t * 8 + i];
        #pragma unroll
        for (int off = 32; off > 0; off >>= 1) part += __shfl_down(part, off);
        if (t == 0) ub[0] = sb2[0] + part;
    }
}

// ---------- fused KNN + per-group MLP (4 groups/block, 512 threads) ----------
#define KCAP 2048
__global__ __launch_bounds__(512, 4) void mlp_kernel(
    const float* __restrict__ xyz, const int* __restrict__ cidx,
    float* __restrict__ out_center,
    const short* __restrict__ w1fh,
    const float* __restrict__ sc1, const float* __restrict__ shb1,
    const short* __restrict__ w2fh,
    const float* __restrict__ b2,
    const float* __restrict__ sw1, const float* __restrict__ sb1,
    const short* __restrict__ Pfh, const float* __restrict__ bc3,
    const short* __restrict__ w3fh,
    const float* __restrict__ sc2, const float* __restrict__ sh2,
    const float* __restrict__ u, const float* __restrict__ ubp,
    short* __restrict__ yh)
{
    __shared__ __align__(16) char smem[71296];
    short* x1 = (short*)smem;                    // [128][128] bf16 swizzled
    short* x2 = (short*)smem;                    // [128][256] bf16 swizzled (overlays x1)
    unsigned* cu = (unsigned*)smem;              // KNN phase: 8KB (region dead then)
    unsigned short* cix = (unsigned short*)(smem + 8192);  // 4KB
    short* feat = (short*)(smem + 32768);        // [128][40] h(0-15)/l(16-31), 10240B
    short* poolA = (short*)(smem + 65536);       // [8][256] bf16 swizzled, 4KB
    float* scs = (float*)(smem + 69632);         // [128]
    float* sms = (float*)(smem + 70144);         // [128]
    int* kidx = (int*)(smem + 70656);            // [128]
    unsigned* Tws = (unsigned*)(smem + 71168);   // [8]
    unsigned* cntp = (unsigned*)(smem + 71200);

    int gb = blockIdx.x * 4;
    int bq = gb >> 9;
    int t = threadIdx.x;
    int lane = t & 63, wv = t >> 6, q = lane >> 4, r = lane & 15;
    const float* xb = xyz + (size_t)bq * 8192 * 3;

    // ================= PK: KNN for the block's 4 groups =================
    if (t == 0) *cntp = 0;
    for (int g = 0; g < 4; ++g) {
        int gg = gb + g;
        int ci = cidx[gg];
        float cx = xb[ci * 3 + 0], cy = xb[ci * 3 + 1], cz = xb[ci * 3 + 2];
        float c2 = cx * cx + cy * cy + cz * cz;
        if (t < 3) out_center[gg * 3 + t] = xb[ci * 3 + t];

        const float4* p4 = (const float4*)xb + (size_t)t * 12;
        unsigned ue[16];
        unsigned vmin = 0xffffffffu;
        #pragma unroll
        for (int ii = 0; ii < 4; ++ii) {
            float4 v0 = p4[ii * 3 + 0];
            float4 v1 = p4[ii * 3 + 1];
            float4 v2 = p4[ii * 3 + 2];
            float px[4], py[4], pz[4];
            px[0] = v0.x; py[0] = v0.y; pz[0] = v0.z;
            px[1] = v0.w; py[1] = v1.x; pz[1] = v1.y;
            px[2] = v1.z; py[2] = v1.w; pz[2] = v2.x;
            px[3] = v2.y; py[3] = v2.z; pz[3] = v2.w;
            #pragma unroll
            for (int m = 0; m < 4; ++m) {
                float dx = px[m], dy = py[m], dz = pz[m];
                float n2 = dx * dx + dy * dy + dz * dz;
                float d = c2 + n2 - 2.f * (cx * dx + cy * dy + cz * dz);
                unsigned uu = __float_as_uint(d);
                uu = (uu & 0x80000000u) ? ~uu : (uu | 0x80000000u);
                ue[ii * 4 + m] = uu;
                vmin = min(vmin, uu);
            }
        }
        // wave bitonic sort of 64 thread-mins
        unsigned v = vmin;
        #pragma unroll
        for (int k = 2; k <= 64; k <<= 1) {
            #pragma unroll
            for (int jj = k >> 1; jj > 0; jj >>= 1) {
                unsigned o = __shfl_xor(v, jj);
                bool dir_asc = ((lane & k) == 0) || (k == 64);
                bool lower = (lane & jj) == 0;
                bool take_min = (lower == dir_asc);
                unsigned mn = min(v, o), mx = max(v, o);
                v = take_min ? mn : mx;
            }
        }
        unsigned Tw = __shfl(v, 31);
        if (lane == 0) Tws[wv] = Tw;
        __syncthreads();
        unsigned T = Tws[0];
        #pragma unroll
        for (int j = 1; j < 8; ++j) T = min(T, Tws[j]);
        // collect candidates <= T
        #pragma unroll
        for (int i = 0; i < 16; ++i) {
            if (ue[i] <= T) {
                unsigned pos = atomicAdd(cntp, 1u);
                if (pos < KCAP) {
                    cu[pos] = ue[i];
                    cix[pos] = (unsigned short)(t * 16 + i);
                }
            }
        }
        __syncthreads();
        int C = (int)min(*cntp, (unsigned)KCAP);
        for (int cc = t; cc < C; cc += 512) {
            unsigned uc = cu[cc];
            unsigned short icd = cix[cc];
            int rank = 0;
            for (int j = 0; j < C; ++j) {
                unsigned uj = cu[j];
                rank += (uj < uc) || (uj == uc && cix[j] < icd);
            }
            if (rank < 32) kidx[g * 32 + rank] = (int)icd;
        }
        __syncthreads();
        if (t == 0) *cntp = 0;
    }

    // P1: feat gather -> feat [128][40] (h c0-15, l c16-31; pads zeroed)
    if (t < 128) {
        int gg = t >> 5;
        int ci = cidx[gb + gg];
        float cxx = xb[ci * 3 + 0], cyy = xb[ci * 3 + 1], czz = xb[ci * 3 + 2];
        int n = kidx[t];
        float nx = xb[n * 3 + 0], ny = xb[n * 3 + 1], nz = xb[n * 3 + 2];
        float rx = cxx - nx, ry = cyy - ny, rz = czz - nz;
        float rd = sqrtf(rx * rx + ry * ry + rz * rz);
        float f[10];
        f[0] = rd; f[1] = rx; f[2] = ry; f[3] = rz;
        f[4] = cxx; f[5] = cyy; f[6] = czz;
        f[7] = nx; f[8] = ny; f[9] = nz;
        unsigned* fr = (unsigned*)(feat + t * 40);
        short h0, l0, h1, l1;
        #pragma unroll
        for (int c = 0; c < 10; c += 2) {
            bsplit(f[c], h0, l0);
            bsplit(f[c + 1], h1, l1);
            fr[c >> 1] = pack2(h0, h1);          // h at shorts c, c+1
            fr[8 + (c >> 1)] = pack2(l0, l1);    // l at shorts 16+c, 16+c+1
        }
        fr[5] = 0; fr[6] = 0; fr[7] = 0;         // h pad c10..15
        fr[13] = 0; fr[14] = 0; fr[15] = 0;      // l pad c26..31
    }
    if (t < 128) scs[t] = sb1[0];
    __syncthreads();

    // P2: conv1 via MFMA: M=128, N=128 (wave: 1 ct), K=32 (10 real)
    {
        f32x4 acc1[8];
        #pragma unroll
        for (int rt = 0; rt < 8; ++rt) acc1[rt] = (f32x4){0.f, 0.f, 0.f, 0.f};
        bf16x8 bw = *(const bf16x8*)(w1fh + ((size_t)wv * 64 + lane) * 8);
        bf16x8 zerov = (bf16x8){0, 0, 0, 0, 0, 0, 0, 0};
        #pragma unroll
        for (int rt = 0; rt < 8; ++rt) {
            int row = rt * 16 + r;
            bf16x8 ah = zerov, al = zerov;
            if (q < 2) {
                ah = *(const bf16x8*)(feat + row * 40 + q * 8);
                al = *(const bf16x8*)(feat + row * 40 + 16 + q * 8);
            }
            acc1[rt] = MFMA16(al, bw, acc1[rt]);
            acc1[rt] = MFMA16(ah, bw, acc1[rt]);
        }
        int o = wv * 16 + r;
        float s1v = sc1[o], sbv = shb1[o];
        #pragma unroll
        for (int rt = 0; rt < 8; ++rt)
            #pragma unroll
            for (int j = 0; j < 4; ++j) {
                int row = rt * 16 + q * 4 + j;
                float vv = fmaxf(acc1[rt][j] * s1v + sbv, 0.f);
                x1[row * 128 + (o ^ ((row & 7) << 3))] = f2bf(vv);
            }
    }
    __syncthreads();

    // P3: conv2 via MFMA (hi weights): M=128, N=256 (wave: 2 ct), K=128
    f32x4 acc2[8][2];
    #pragma unroll
    for (int rt = 0; rt < 8; ++rt)
        #pragma unroll
        for (int ctl = 0; ctl < 2; ++ctl) {
            float bv = b2[(wv * 2 + ctl) * 16 + r];
            acc2[rt][ctl] = (f32x4){bv, bv, bv, bv};
        }
    #pragma unroll
    for (int ks = 0; ks < 4; ++ks) {
        bf16x8 af[8];
        #pragma unroll
        for (int rt = 0; rt < 8; ++rt) {
            int row = rt * 16 + r;
            int kk = ks * 32 + q * 8;
            af[rt] = *(const bf16x8*)(x1 + row * 128 + (kk ^ ((row & 7) << 3)));
        }
        #pragma unroll
        for (int ctl = 0; ctl < 2; ++ctl) {
            int ct = wv * 2 + ctl;
            size_t woff = ((size_t)(ct * 4 + ks) * 64 + lane) * 8;
            bf16x8 bh = *(const bf16x8*)(w2fh + woff);
            #pragma unroll
            for (int rt = 0; rt < 8; ++rt)
                acc2[rt][ctl] = MFMA16(af[rt], bh, acc2[rt][ctl]);
        }
    }
    // attn1 score partials
    {
        float sw1v[2];
        #pragma unroll
        for (int ctl = 0; ctl < 2; ++ctl) sw1v[ctl] = sw1[(wv * 2 + ctl) * 16 + r];
        #pragma unroll
        for (int rt = 0; rt < 8; ++rt)
            #pragma unroll
            for (int j = 0; j < 4; ++j) {
                float s = sw1v[0] * acc2[rt][0][j] + sw1v[1] * acc2[rt][1][j];
                s += __shfl_xor(s, 1); s += __shfl_xor(s, 2);
                s += __shfl_xor(s, 4); s += __shfl_xor(s, 8);
                if (r == 0) atomicAdd(&scs[rt * 16 + q * 4 + j], s);
            }
    }
    __syncthreads();

    // P4: wave-parallel softmax1 + x2 store
    if (wv < 4 && lane < 32) {
        float s = scs[wv * 32 + lane];
        float mx = s;
        mx = fmaxf(mx, __shfl_xor(mx, 16));
        mx = fmaxf(mx, __shfl_xor(mx, 8));
        mx = fmaxf(mx, __shfl_xor(mx, 4));
        mx = fmaxf(mx, __shfl_xor(mx, 2));
        mx = fmaxf(mx, __shfl_xor(mx, 1));
        float e = expf(s - mx);
        float sum = e;
        sum += __shfl_xor(sum, 16);
        sum += __shfl_xor(sum, 8);
        sum += __shfl_xor(sum, 4);
        sum += __shfl_xor(sum, 2);
        sum += __shfl_xor(sum, 1);
        sms[wv * 32 + lane] = e / sum;
    }
    #pragma unroll
    for (int rt = 0; rt < 8; ++rt)
        #pragma unroll
        for (int ctl = 0; ctl < 2; ++ctl) {
            int ch = (wv * 2 + ctl) * 16 + r;
            #pragma unroll
            for (int j = 0; j < 4; ++j) {
                int row = rt * 16 + q * 4 + j;
                x2[row * 256 + (ch ^ ((row & 7) << 3))] = f2bf(acc2[rt][ctl][j]);
            }
        }
    __syncthreads();

    // P5: pool1 -> poolA bf16 rows (hi: gg, lo: gg+4); scs re-init for attn2
    {
        #pragma unroll
        for (int ctl = 0; ctl < 2; ++ctl)
            #pragma unroll
            for (int gg = 0; gg < 4; ++gg) {
                float p = 0.f;
                #pragma unroll
                for (int rr = 0; rr < 2; ++rr) {
                    int rt = gg * 2 + rr;
                    #pragma unroll
                    for (int j = 0; j < 4; ++j)
                        p += sms[rt * 16 + q * 4 + j] * acc2[rt][ctl][j];
                }
                p += __shfl_xor(p, 16);
                p += __shfl_xor(p, 32);
                if (q == 0) {
                    int ch = (wv * 2 + ctl) * 16 + r;
                    short h, l; bsplit(p, h, l);
                    poolA[gg * 256 + (ch ^ (gg << 3))] = h;
                    poolA[(gg + 4) * 256 + (ch ^ ((gg + 4) << 3))] = l;
                }
            }
        if (t < 128) scs[t] = ubp[0];
    }
    __syncthreads();

    // P6: pool@P via MFMA (registers only; A rows 0-7 = poolA hi/lo, 8-15 zero)
    float fgv[4][4];   // [ctl][group]
    float bc3v[4];
    {
        f32x4 accP[4];
        #pragma unroll
        for (int ctl = 0; ctl < 4; ++ctl) accP[ctl] = (f32x4){0.f, 0.f, 0.f, 0.f};
        #pragma unroll
        for (int ks = 0; ks < 8; ++ks) {
            int kk = ks * 32 + q * 8;
            bf16x8 pa;
            if (r < 8) pa = *(const bf16x8*)(poolA + r * 256 + (kk ^ (r << 3)));
            else pa = (bf16x8){0, 0, 0, 0, 0, 0, 0, 0};
            #pragma unroll
            for (int ctl = 0; ctl < 4; ++ctl) {
                size_t woff = ((size_t)((wv * 4 + ctl) * 8 + ks) * 64 + lane) * 8;
                bf16x8 ph = *(const bf16x8*)(Pfh + woff);
                accP[ctl] = MFMA16(pa, ph, accP[ctl]);
            }
        }
        #pragma unroll
        for (int ctl = 0; ctl < 4; ++ctl) {
            bc3v[ctl] = bc3[(wv * 4 + ctl) * 16 + r];
            #pragma unroll
            for (int j = 0; j < 4; ++j) {
                float x = accP[ctl][j];
                x += __shfl_xor(x, 16);
                x += __shfl_xor(x, 32);
                fgv[ctl][j] = x;
            }
        }
    }

    // P7: conv3 via MFMA (hi weights): M=128, N=512, K=256; init = fgv + bc3
    f32x4 acc3[8][4];
    #pragma unroll
    for (int rt = 0; rt < 8; ++rt) {
        int gg = rt >> 1;
        #pragma unroll
        for (int ctl = 0; ctl < 4; ++ctl) {
            float fp = fgv[ctl][gg] + bc3v[ctl];
            acc3[rt][ctl] = (f32x4){fp, fp, fp, fp};
        }
    }
    #pragma unroll
    for (int ks = 0; ks < 8; ++ks) {
        bf16x8 af[8];
        #pragma unroll
        for (int rt = 0; rt < 8; ++rt) {
            int row = rt * 16 + r;
            int kk = ks * 32 + q * 8;
            af[rt] = *(const bf16x8*)(x2 + row * 256 + (kk ^ ((row & 7) << 3)));
        }
        #pragma unroll
        for (int ctl = 0; ctl < 4; ++ctl) {
            int ct = wv * 4 + ctl;
            size_t woff = ((size_t)(ct * 8 + ks) * 64 + lane) * 8;
            bf16x8 bh = *(const bf16x8*)(w3fh + woff);
            #pragma unroll
            for (int rt = 0; rt < 8; ++rt)
                acc3[rt][ctl] = MFMA16(af[rt], bh, acc3[rt][ctl]);
        }
    }
    // BN2 + ReLU; attn2 score partials
    float uv[4];
    {
        #pragma unroll
        for (int ctl = 0; ctl < 4; ++ctl) {
            int ch = (wv * 4 + ctl) * 16 + r;
            float s = sc2[ch], sh = sh2[ch];
            uv[ctl] = u[ch];
            #pragma unroll
            for (int rt = 0; rt < 8; ++rt)
                #pragma unroll
                for (int j = 0; j < 4; ++j)
                    acc3[rt][ctl][j] = fmaxf(acc3[rt][ctl][j] * s + sh, 0.f);
        }
        #pragma unroll
        for (int rt = 0; rt < 8; ++rt)
            #pragma unroll
            for (int j = 0; j < 4; ++j) {
                float s = uv[0] * acc3[rt][0][j] + uv[1] * acc3[rt][1][j]
                        + uv[2] * acc3[rt][2][j] + uv[3] * acc3[rt][3][j];
                s += __shfl_xor(s, 1); s += __shfl_xor(s, 2);
                s += __shfl_xor(s, 4); s += __shfl_xor(s, 8);
                if (r == 0) atomicAdd(&scs[rt * 16 + q * 4 + j], s);
            }
    }
    __syncthreads();

    // P8: wave-parallel softmax2
    if (wv < 4 && lane < 32) {
        float s = scs[wv * 32 + lane];
        float mx = s;
        mx = fmaxf(mx, __shfl_xor(mx, 16));
        mx = fmaxf(mx, __shfl_xor(mx, 8));
        mx = fmaxf(mx, __shfl_xor(mx, 4));
        mx = fmaxf(mx, __shfl_xor(mx, 2));
        mx = fmaxf(mx, __shfl_xor(mx, 1));
        float e = expf(s - mx);
        float sum = e;
        sum += __shfl_xor(sum, 16);
        sum += __shfl_xor(sum, 8);
        sum += __shfl_xor(sum, 4);
        sum += __shfl_xor(sum, 2);
        sum += __shfl_xor(sum, 1);
        sms[wv * 32 + lane] = e / sum;
    }
    __syncthreads();

    // P9: y[g][ch] = sum_k s[k]*x4[k][ch] -> global bf16
    {
        #pragma unroll
        for (int ctl = 0; ctl < 4; ++ctl)
            #pragma unroll
            for (int gg = 0; gg < 4; ++gg) {
                float p = 0.f;
                #pragma unroll
                for (int rr = 0; rr < 2; ++rr) {
                    int rt = gg * 2 + rr;
                    #pragma unroll
                    for (int j = 0; j < 4; ++j)
                        p += sms[rt * 16 + q * 4 + j] * acc3[rt][ctl][j];
                }
                p += __shfl_xor(p, 16);
                p += __shfl_xor(p, 32);
                if (q == 0) {
                    int grow = gb + gg;
                    int ch = (wv * 4 + ctl) * 16 + r;
                    yh[(size_t)grow * 512 + ch] = f2bf(p);
                }
            }
    }
}

// ---------------- fg2 GEMM: out = bb + y @ MT (hi-only) ----------------------
__global__ __launch_bounds__(256) void fg2_kernel(
    const short* __restrict__ yh,
    const short* __restrict__ MTfh,
    const float* __restrict__ bb, float* __restrict__ out_fg2)
{
    int gbase = blockIdx.x * 16;
    int t = threadIdx.x;
    int lane = t & 63, wv = t >> 6, q = lane >> 4, r = lane & 15;
    f32x4 acc[8];
    #pragma unroll
    for (int ctl = 0; ctl < 8; ++ctl) {
        float bv = bb[(wv * 8 + ctl) * 16 + r];
        acc[ctl] = (f32x4){bv, bv, bv, bv};
    }
    #pragma unroll
    for (int ks = 0; ks < 16; ++ks) {
        bf16x8 af = *(const bf16x8*)(yh + (size_t)(gbase + r) * 512 + ks * 32 + q * 8);
        #pragma unroll
        for (int ctl = 0; ctl < 8; ++ctl) {
            int ct = wv * 8 + ctl;
            size_t woff = ((size_t)(ct * 16 + ks) * 64 + lane) * 8;
            bf16x8 bh = *(const bf16x8*)(MTfh + woff);
            acc[ctl] = MFMA16(af, bh, acc[ctl]);
        }
    }
    #pragma unroll
    for (int ctl = 0; ctl < 8; ++ctl) {
        int ch = (wv * 8 + ctl) * 16 + r;
        #pragma unroll
        for (int j = 0; j < 4; ++j) {
            int grow = gbase + q * 4 + j;
            out_fg2[(size_t)grow * 512 + ch] = acc[ctl][j];
        }
    }
}

extern "C" void kernel_launch(void* const* d_in, const int* in_sizes, int n_in,
                              void* d_out, int out_size, void* d_ws, size_t ws_size,
                              hipStream_t stream) {
    const float* xyz  = (const float*)d_in[0];
    const int*   cidx = (const int*)d_in[1];
    const float* w1   = (const float*)d_in[2];
    const float* b1   = (const float*)d_in[3];
    const float* g1   = (const float*)d_in[4];
    const float* be1  = (const float*)d_in[5];
    const float* m1   = (const float*)d_in[6];
    const float* v1   = (const float*)d_in[7];
    const float* w2   = (const float*)d_in[8];
    const float* b2   = (const float*)d_in[9];
    const float* sw1  = (const float*)d_in[10];
    const float* sb1  = (const float*)d_in[11];
    const float* mw1  = (const float*)d_in[12];
    const float* mb1  = (const float*)d_in[13];
    const float* w3   = (const float*)d_in[14];
    const float* b3   = (const float*)d_in[15];
    const float* g2   = (const float*)d_in[16];
    const float* be2  = (const float*)d_in[17];
    const float* m2   = (const float*)d_in[18];
    const float* v2   = (const float*)d_in[19];
    const float* w4   = (const float*)d_in[20];
    const float* b4   = (const float*)d_in[21];
    const float* sw2  = (const float*)d_in[22];
    const float* sb2  = (const float*)d_in[23];
    const float* mw2  = (const float*)d_in[24];
    const float* mb2  = (const float*)d_in[25];

    float* out = (float*)d_out;
    char* ws = (char*)d_ws;
    short* w2fh = (short*)(ws + 524288);         // 65536
    short* w3fh = (short*)(ws + 655360);         // 262144
    short* Pfh  = (short*)(ws + 1179648);        // 262144
    short* w1fh = (short*)(ws + 1441792);        // 8192
    float* bc3  = (float*)(ws + 1703936);        // 2048
    float* sc1  = (float*)(ws + 1705984);        // 512
    float* shb1 = (float*)(ws + 1706496);        // 512
    float* sc2  = (float*)(ws + 1707008);        // 2048
    float* sh2  = (float*)(ws + 1709056);        // 2048
    float* u    = (float*)(ws + 1711104);        // 2048
    float* bb   = (float*)(ws + 1713152);        // 2048
    float* ub   = (float*)(ws + 1715200);        // 256 (pad)
    short* MTfh = (short*)(ws + 1715456);        // 524288
    short* yh   = (short*)(ws + 2764032);        // 4194304

    prep_kernel<<<1027, 256, 0, stream>>>(w1, b1, w2, w3, mw1, mw2, w4, b4,
                                          sw2, sb2, mb2, mb1, b3,
                                          g1, be1, m1, v1, g2, be2, m2, v2,
                                          w1fh, w2fh, w3fh, Pfh, MTfh,
                                          sc1, shb1, sc2, sh2, u, bb, ub, bc3);
    mlp_kernel<<<1024, 512, 0, stream>>>(xyz, cidx, out,
                                         w1fh, sc1, shb1, w2fh, b2,
                                         sw1, sb1, Pfh, bc3, w3fh,
                                         sc2, sh2, u, ub, yh);
    fg2_kernel<<<256, 256, 0, stream>>>(yh, MTfh, bb, out + 12288);
}

// Round 9
// 688.937 us; speedup vs baseline: 1.2669x; 1.2669x over previous
//
#include <hip/hip_runtime.h>
#include <math.h>

#define EPSV 1e-5f

typedef __attribute__((ext_vector_type(8))) short bf16x8;
typedef __attribute__((ext_vector_type(4))) float f32x4;

#define MFMA16(a, b, c) __builtin_amdgcn_mfma_f32_16x16x32_bf16(a, b, c, 0, 0, 0)

__device__ __forceinline__ short f2bf(float x) {
    unsigned u = __float_as_uint(x);
    unsigned r = (u + 0x7fffu + ((u >> 16) & 1u)) >> 16;
    return (short)r;
}
__device__ __forceinline__ float bf2f(short h) {
    return __uint_as_float(((unsigned)(unsigned short)h) << 16);
}
__device__ __forceinline__ void bsplit(float x, short& h, short& l) {
    h = f2bf(x);
    l = f2bf(x - bf2f(h));
}
__device__ __forceinline__ unsigned pack2(short a, short b) {
    return ((unsigned)(unsigned short)a) | (((unsigned)(unsigned short)b) << 16);
}

// ============ prep: weight packing + folds, roles by blockIdx (1027) =========
__global__ __launch_bounds__(256) void prep_kernel(
    const float* __restrict__ w1, const float* __restrict__ b1,
    const float* __restrict__ w2, const float* __restrict__ w3,
    const float* __restrict__ mw1, const float* __restrict__ mw2,
    const float* __restrict__ w4, const float* __restrict__ b4,
    const float* __restrict__ sw2, const float* __restrict__ sb2,
    const float* __restrict__ mb2, const float* __restrict__ mb1,
    const float* __restrict__ b3,
    const float* __restrict__ g1, const float* __restrict__ be1,
    const float* __restrict__ m1, const float* __restrict__ v1,
    const float* __restrict__ g2, const float* __restrict__ be2,
    const float* __restrict__ m2, const float* __restrict__ v2,
    short* __restrict__ w1fh, short* __restrict__ w2fh, short* __restrict__ w3fh,
    short* __restrict__ Pfh, short* __restrict__ MTfh,
    float* __restrict__ sc1, float* __restrict__ shb1,
    float* __restrict__ sc2, float* __restrict__ sh2,
    float* __restrict__ u, float* __restrict__ bb, float* __restrict__ ub,
    float* __restrict__ bc3)
{
    __shared__ __align__(16) float shm[520];
    int B = blockIdx.x, t = threadIdx.x;
    int lane = t & 63, w = t >> 6;

    if (B < 256) {
        float* col = shm;
        int c = B;
        col[t] = mw1[t * 256 + c];
        __syncthreads();
        int ks = c >> 5, qq = (c >> 3) & 3, jj = c & 7;
        for (int oo = t; oo < 512; oo += 256) {
            float acc = 0.f;
            for (int d = 0; d < 256; ++d) acc += col[d] * w3[oo * 512 + d];
            int ct = oo >> 4;
            size_t idx = ((size_t)(ct * 8 + ks) * 64 + qq * 16 + (oo & 15)) * 8 + jj;
            Pfh[idx] = f2bf(acc);
        }
        return;
    }

    if (B < 768) {
        float* row = shm;
        int qq = B - 256;
        row[t] = mw2[(size_t)qq * 512 + t];
        row[t + 256] = mw2[(size_t)qq * 512 + t + 256];
        __syncthreads();
        float a0 = 0.f, a1 = 0.f;
        for (int o = 0; o < 512; ++o) {
            float m = row[o];
            a0 += m * w4[o * 512 + t];
            a1 += m * w4[o * 512 + t + 256];
        }
        int ct = qq >> 4, nl = qq & 15;
        {
            int k = t;
            size_t i0 = (((size_t)(ct * 16 + (k >> 5))) << 9)
                      | ((((k >> 3) & 3) * 16 + nl) << 3) | (k & 7);
            MTfh[i0] = f2bf(a0);
        }
        {
            int k = t + 256;
            size_t i1 = (((size_t)(ct * 16 + (k >> 5))) << 9)
                      | ((((k >> 3) & 3) * 16 + nl) << 3) | (k & 7);
            MTfh[i1] = f2bf(a1);
        }
        return;
    }

    if (B < 896) {
        int tid = (B - 768) * 256 + t;
        {
            int i = tid;
            int j = i & 7, ln = (i >> 3) & 63, rest = i >> 9;
            int ks = rest & 3, ct = rest >> 2;
            int o = ct * 16 + (ln & 15);
            int k = ks * 32 + (ln >> 4) * 8 + j;
            w2fh[i] = f2bf(w2[o * 128 + k]);
        }
        #pragma unroll
        for (int s = 0; s < 4; ++s) {
            int i = tid + s * 32768;
            int j = i & 7, ln = (i >> 3) & 63, rest = i >> 9;
            int ks = rest & 7, ct = rest >> 3;
            int o = ct * 16 + (ln & 15);
            int c = 256 + ks * 32 + (ln >> 4) * 8 + j;
            w3fh[i] = f2bf(w3[o * 512 + c]);
        }
        return;
    }

    if (B < 960) {
        float* b4s = shm;
        float* red = shm + 512;
        b4s[t] = b4[t];
        b4s[t + 256] = b4[t + 256];
        __syncthreads();
        int q0 = (B - 896) * 8;
        for (int i = 0; i < 8; ++i) {
            int q = q0 + i;
            float part = mw2[(size_t)q * 512 + t] * b4s[t]
                       + mw2[(size_t)q * 512 + 256 + t] * b4s[256 + t];
            #pragma unroll
            for (int off = 32; off > 0; off >>= 1) part += __shfl_down(part, off);
            if (lane == 0) red[w] = part;
            __syncthreads();
            if (t == 0) bb[q] = mb2[q] + red[0] + red[1] + red[2] + red[3];
            __syncthreads();
        }
        return;
    }

    if (B < 1024) {
        float* mb1s = shm;
        float* red = shm + 512;
        mb1s[t] = mb1[t];
        __syncthreads();
        int o0 = (B - 960) * 8;
        for (int i = 0; i < 8; ++i) {
            int o = o0 + i;
            float part = w3[(size_t)o * 512 + t] * mb1s[t];
            #pragma unroll
            for (int off = 32; off > 0; off >>= 1) part += __shfl_down(part, off);
            if (lane == 0) red[w] = part;
            __syncthreads();
            if (t == 0) bc3[o] = b3[o] + red[0] + red[1] + red[2] + red[3];
            __syncthreads();
        }
        return;
    }

    if (B < 1026) {
        int c = (B - 1024) * 256 + t;
        float acc = 0.f;
        for (int o = 0; o < 512; ++o) acc += sw2[o] * w4[o * 512 + c];
        u[c] = acc;
        return;
    }

    if (t < 128) {
        float s = g1[t] * rsqrtf(v1[t] + EPSV);
        float sh = be1[t] - m1[t] * s;
        sc1[t] = s;
        shb1[t] = b1[t] * s + sh;
    }
    {
        float s = g2[t] * rsqrtf(v2[t] + EPSV);
        sc2[t] = s; sh2[t] = be2[t] - m2[t] * s;
        s = g2[t + 256] * rsqrtf(v2[t + 256] + EPSV);
        sc2[t + 256] = s; sh2[t + 256] = be2[t + 256] - m2[t + 256] * s;
    }
    #pragma unroll
    for (int s = 0; s < 16; ++s) {
        int i = t + s * 256;
        int j = i & 7, ln = (i >> 3) & 63, ct = i >> 9;
        int o = ct * 16 + (ln & 15);
        int k = (ln >> 4) * 8 + j;
        w1fh[i] = (k < 10) ? f2bf(w1[o * 10 + k]) : (short)0;
    }
    if (t < 64) {
        float part = 0.f;
        #pragma unroll
        for (int i = 0; i < 8; ++i) part += sw2[t * 8 + i] * b4[t * 8 + i];
        #pragma unroll
        for (int off = 32; off > 0; off >>= 1) part += __shfl_down(part, off);
        if (t == 0) ub[0] = sb2[0] + part;
    }
}

// ---------- fused KNN + per-group MLP (4 groups/block, 512 threads) ----------
#define KCAP 2048
__global__ __launch_bounds__(512) void mlp_kernel(
    const float* __restrict__ xyz, const int* __restrict__ cidx,
    float* __restrict__ out_center,
    const short* __restrict__ w1fh,
    const float* __restrict__ sc1, const float* __restrict__ shb1,
    const short* __restrict__ w2fh,
    const float* __restrict__ b2,
    const float* __restrict__ sw1, const float* __restrict__ sb1,
    const short* __restrict__ Pfh, const float* __restrict__ bc3,
    const short* __restrict__ w3fh,
    const float* __restrict__ sc2, const float* __restrict__ sh2,
    const float* __restrict__ u, const float* __restrict__ ubp,
    short* __restrict__ yh)
{
    __shared__ __align__(16) char smem[71296];
    short* x1 = (short*)smem;                    // [128][128] bf16 swizzled
    short* x2 = (short*)smem;                    // [128][256] bf16 swizzled (overlays x1)
    unsigned* cu = (unsigned*)smem;              // KNN phase: 8KB (region dead then)
    unsigned short* cix = (unsigned short*)(smem + 8192);  // 4KB
    short* feat = (short*)(smem + 32768);        // [128][40] h(0-15)/l(16-31), 10240B
    short* poolA = (short*)(smem + 65536);       // [8][256] bf16 swizzled, 4KB
    float* scs = (float*)(smem + 69632);         // [128]
    float* sms = (float*)(smem + 70144);         // [128]
    int* kidx = (int*)(smem + 70656);            // [128]
    unsigned* Tws = (unsigned*)(smem + 71168);   // [8]
    unsigned* cntp = (unsigned*)(smem + 71200);

    int gb = blockIdx.x * 4;
    int bq = gb >> 9;
    int t = threadIdx.x;
    int lane = t & 63, wv = t >> 6, q = lane >> 4, r = lane & 15;
    const float* xb = xyz + (size_t)bq * 8192 * 3;

    // ================= PK: KNN for the block's 4 groups =================
    if (t == 0) *cntp = 0;
    for (int g = 0; g < 4; ++g) {
        int gg = gb + g;
        int ci = cidx[gg];
        float cx = xb[ci * 3 + 0], cy = xb[ci * 3 + 1], cz = xb[ci * 3 + 2];
        float c2 = cx * cx + cy * cy + cz * cz;
        if (t < 3) out_center[gg * 3 + t] = xb[ci * 3 + t];

        const float4* p4 = (const float4*)xb + (size_t)t * 12;
        unsigned ue[16];
        unsigned vmin = 0xffffffffu;
        #pragma unroll
        for (int ii = 0; ii < 4; ++ii) {
            float4 v0 = p4[ii * 3 + 0];
            float4 v1 = p4[ii * 3 + 1];
            float4 v2 = p4[ii * 3 + 2];
            float px[4], py[4], pz[4];
            px[0] = v0.x; py[0] = v0.y; pz[0] = v0.z;
            px[1] = v0.w; py[1] = v1.x; pz[1] = v1.y;
            px[2] = v1.z; py[2] = v1.w; pz[2] = v2.x;
            px[3] = v2.y; py[3] = v2.z; pz[3] = v2.w;
            #pragma unroll
            for (int m = 0; m < 4; ++m) {
                float dx = px[m], dy = py[m], dz = pz[m];
                float n2 = dx * dx + dy * dy + dz * dz;
                float d = c2 + n2 - 2.f * (cx * dx + cy * dy + cz * dz);
                unsigned uu = __float_as_uint(d);
                uu = (uu & 0x80000000u) ? ~uu : (uu | 0x80000000u);
                ue[ii * 4 + m] = uu;
                vmin = min(vmin, uu);
            }
        }
        unsigned v = vmin;
        #pragma unroll
        for (int k = 2; k <= 64; k <<= 1) {
            #pragma unroll
            for (int jj = k >> 1; jj > 0; jj >>= 1) {
                unsigned o = __shfl_xor(v, jj);
                bool dir_asc = ((lane & k) == 0) || (k == 64);
                bool lower = (lane & jj) == 0;
                bool take_min = (lower == dir_asc);
                unsigned mn = min(v, o), mx = max(v, o);
                v = take_min ? mn : mx;
            }
        }
        unsigned Tw = __shfl(v, 31);
        if (lane == 0) Tws[wv] = Tw;
        __syncthreads();
        unsigned T = Tws[0];
        #pragma unroll
        for (int j = 1; j < 8; ++j) T = min(T, Tws[j]);
        #pragma unroll
        for (int i = 0; i < 16; ++i) {
            if (ue[i] <= T) {
                unsigned pos = atomicAdd(cntp, 1u);
                if (pos < KCAP) {
                    cu[pos] = ue[i];
                    cix[pos] = (unsigned short)(t * 16 + i);
                }
            }
        }
        __syncthreads();
        int C = (int)min(*cntp, (unsigned)KCAP);
        for (int cc = t; cc < C; cc += 512) {
            unsigned uc = cu[cc];
            unsigned short icd = cix[cc];
            int rank = 0;
            for (int j = 0; j < C; ++j) {
                unsigned uj = cu[j];
                rank += (uj < uc) || (uj == uc && cix[j] < icd);
            }
            if (rank < 32) kidx[g * 32 + rank] = (int)icd;
        }
        __syncthreads();
        if (t == 0) *cntp = 0;
    }

    // P1: feat gather -> feat [128][40] (h c0-15, l c16-31; pads zeroed)
    if (t < 128) {
        int gg = t >> 5;
        int ci = cidx[gb + gg];
        float cxx = xb[ci * 3 + 0], cyy = xb[ci * 3 + 1], czz = xb[ci * 3 + 2];
        int n = kidx[t];
        float nx = xb[n * 3 + 0], ny = xb[n * 3 + 1], nz = xb[n * 3 + 2];
        float rx = cxx - nx, ry = cyy - ny, rz = czz - nz;
        float rd = sqrtf(rx * rx + ry * ry + rz * rz);
        float f[10];
        f[0] = rd; f[1] = rx; f[2] = ry; f[3] = rz;
        f[4] = cxx; f[5] = cyy; f[6] = czz;
        f[7] = nx; f[8] = ny; f[9] = nz;
        unsigned* fr = (unsigned*)(feat + t * 40);
        short h0, l0, h1, l1;
        #pragma unroll
        for (int c = 0; c < 10; c += 2) {
            bsplit(f[c], h0, l0);
            bsplit(f[c + 1], h1, l1);
            fr[c >> 1] = pack2(h0, h1);
            fr[8 + (c >> 1)] = pack2(l0, l1);
        }
        fr[5] = 0; fr[6] = 0; fr[7] = 0;
        fr[13] = 0; fr[14] = 0; fr[15] = 0;
    }
    if (t < 128) scs[t] = sb1[0];
    __syncthreads();

    // P2: conv1 via MFMA: M=128, N=128 (wave: 1 ct), K=32 (10 real)
    {
        f32x4 acc1[8];
        #pragma unroll
        for (int rt = 0; rt < 8; ++rt) acc1[rt] = (f32x4){0.f, 0.f, 0.f, 0.f};
        bf16x8 bw = *(const bf16x8*)(w1fh + ((size_t)wv * 64 + lane) * 8);
        bf16x8 zerov = (bf16x8){0, 0, 0, 0, 0, 0, 0, 0};
        #pragma unroll
        for (int rt = 0; rt < 8; ++rt) {
            int row = rt * 16 + r;
            bf16x8 ah = zerov, al = zerov;
            if (q < 2) {
                ah = *(const bf16x8*)(feat + row * 40 + q * 8);
                al = *(const bf16x8*)(feat + row * 40 + 16 + q * 8);
            }
            acc1[rt] = MFMA16(al, bw, acc1[rt]);
            acc1[rt] = MFMA16(ah, bw, acc1[rt]);
        }
        int o = wv * 16 + r;
        float s1v = sc1[o], sbv = shb1[o];
        #pragma unroll
        for (int rt = 0; rt < 8; ++rt)
            #pragma unroll
            for (int j = 0; j < 4; ++j) {
                int row = rt * 16 + q * 4 + j;
                float vv = fmaxf(acc1[rt][j] * s1v + sbv, 0.f);
                x1[row * 128 + (o ^ ((row & 7) << 3))] = f2bf(vv);
            }
    }
    __syncthreads();

    // P3: conv2 via MFMA (hi weights): M=128, N=256 (wave: 2 ct), K=128
    f32x4 acc2[8][2];
    #pragma unroll
    for (int rt = 0; rt < 8; ++rt)
        #pragma unroll
        for (int ctl = 0; ctl < 2; ++ctl) {
            float bv = b2[(wv * 2 + ctl) * 16 + r];
            acc2[rt][ctl] = (f32x4){bv, bv, bv, bv};
        }
    #pragma unroll
    for (int ks = 0; ks < 4; ++ks) {
        bf16x8 af[8];
        #pragma unroll
        for (int rt = 0; rt < 8; ++rt) {
            int row = rt * 16 + r;
            int kk = ks * 32 + q * 8;
            af[rt] = *(const bf16x8*)(x1 + row * 128 + (kk ^ ((row & 7) << 3)));
        }
        #pragma unroll
        for (int ctl = 0; ctl < 2; ++ctl) {
            int ct = wv * 2 + ctl;
            size_t woff = ((size_t)(ct * 4 + ks) * 64 + lane) * 8;
            bf16x8 bh = *(const bf16x8*)(w2fh + woff);
            #pragma unroll
            for (int rt = 0; rt < 8; ++rt)
                acc2[rt][ctl] = MFMA16(af[rt], bh, acc2[rt][ctl]);
        }
    }
    // attn1 score partials
    {
        float sw1v[2];
        #pragma unroll
        for (int ctl = 0; ctl < 2; ++ctl) sw1v[ctl] = sw1[(wv * 2 + ctl) * 16 + r];
        #pragma unroll
        for (int rt = 0; rt < 8; ++rt)
            #pragma unroll
            for (int j = 0; j < 4; ++j) {
                float s = sw1v[0] * acc2[rt][0][j] + sw1v[1] * acc2[rt][1][j];
                s += __shfl_xor(s, 1); s += __shfl_xor(s, 2);
                s += __shfl_xor(s, 4); s += __shfl_xor(s, 8);
                if (r == 0) atomicAdd(&scs[rt * 16 + q * 4 + j], s);
            }
    }
    __syncthreads();

    // P4: wave-parallel softmax1 + x2 store
    if (wv < 4 && lane < 32) {
        float s = scs[wv * 32 + lane];
        float mx = s;
        mx = fmaxf(mx, __shfl_xor(mx, 16));
        mx = fmaxf(mx, __shfl_xor(mx, 8));
        mx = fmaxf(mx, __shfl_xor(mx, 4));
        mx = fmaxf(mx, __shfl_xor(mx, 2));
        mx = fmaxf(mx, __shfl_xor(mx, 1));
        float e = expf(s - mx);
        float sum = e;
        sum += __shfl_xor(sum, 16);
        sum += __shfl_xor(sum, 8);
        sum += __shfl_xor(sum, 4);
        sum += __shfl_xor(sum, 2);
        sum += __shfl_xor(sum, 1);
        sms[wv * 32 + lane] = e / sum;
    }
    #pragma unroll
    for (int rt = 0; rt < 8; ++rt)
        #pragma unroll
        for (int ctl = 0; ctl < 2; ++ctl) {
            int ch = (wv * 2 + ctl) * 16 + r;
            #pragma unroll
            for (int j = 0; j < 4; ++j) {
                int row = rt * 16 + q * 4 + j;
                x2[row * 256 + (ch ^ ((row & 7) << 3))] = f2bf(acc2[rt][ctl][j]);
            }
        }
    __syncthreads();

    // P5: pool1 -> poolA bf16 rows (hi: gg, lo: gg+4); scs re-init for attn2
    {
        #pragma unroll
        for (int ctl = 0; ctl < 2; ++ctl)
            #pragma unroll
            for (int gg = 0; gg < 4; ++gg) {
                float p = 0.f;
                #pragma unroll
                for (int rr = 0; rr < 2; ++rr) {
                    int rt = gg * 2 + rr;
                    #pragma unroll
                    for (int j = 0; j < 4; ++j)
                        p += sms[rt * 16 + q * 4 + j] * acc2[rt][ctl][j];
                }
                p += __shfl_xor(p, 16);
                p += __shfl_xor(p, 32);
                if (q == 0) {
                    int ch = (wv * 2 + ctl) * 16 + r;
                    short h, l; bsplit(p, h, l);
                    poolA[gg * 256 + (ch ^ (gg << 3))] = h;
                    poolA[(gg + 4) * 256 + (ch ^ ((gg + 4) << 3))] = l;
                }
            }
        if (t < 128) scs[t] = ubp[0];
    }
    __syncthreads();

    // P6: pool@P via MFMA (registers only; A rows 0-7 = poolA hi/lo, 8-15 zero)
    float fgv[4][4];   // [ctl][group]
    float bc3v[4];
    {
        f32x4 accP[4];
        #pragma unroll
        for (int ctl = 0; ctl < 4; ++ctl) accP[ctl] = (f32x4){0.f, 0.f, 0.f, 0.f};
        #pragma unroll
        for (int ks = 0; ks < 8; ++ks) {
            int kk = ks * 32 + q * 8;
            bf16x8 pa;
            if (r < 8) pa = *(const bf16x8*)(poolA + r * 256 + (kk ^ (r << 3)));
            else pa = (bf16x8){0, 0, 0, 0, 0, 0, 0, 0};
            #pragma unroll
            for (int ctl = 0; ctl < 4; ++ctl) {
                size_t woff = ((size_t)((wv * 4 + ctl) * 8 + ks) * 64 + lane) * 8;
                bf16x8 ph = *(const bf16x8*)(Pfh + woff);
                accP[ctl] = MFMA16(pa, ph, accP[ctl]);
            }
        }
        #pragma unroll
        for (int ctl = 0; ctl < 4; ++ctl) {
            bc3v[ctl] = bc3[(wv * 4 + ctl) * 16 + r];
            #pragma unroll
            for (int j = 0; j < 4; ++j) {
                float x = accP[ctl][j];
                x += __shfl_xor(x, 16);
                x += __shfl_xor(x, 32);
                fgv[ctl][j] = x;
            }
        }
    }

    // P7: conv3 via MFMA (hi weights): M=128, N=512, K=256; init = fgv + bc3
    f32x4 acc3[8][4];
    #pragma unroll
    for (int rt = 0; rt < 8; ++rt) {
        int gg = rt >> 1;
        #pragma unroll
        for (int ctl = 0; ctl < 4; ++ctl) {
            float fp = fgv[ctl][gg] + bc3v[ctl];
            acc3[rt][ctl] = (f32x4){fp, fp, fp, fp};
        }
    }
    #pragma unroll
    for (int ks = 0; ks < 8; ++ks) {
        bf16x8 af[8];
        #pragma unroll
        for (int rt = 0; rt < 8; ++rt) {
            int row = rt * 16 + r;
            int kk = ks * 32 + q * 8;
            af[rt] = *(const bf16x8*)(x2 + row * 256 + (kk ^ ((row & 7) << 3)));
        }
        #pragma unroll
        for (int ctl = 0; ctl < 4; ++ctl) {
            int ct = wv * 4 + ctl;
            size_t woff = ((size_t)(ct * 8 + ks) * 64 + lane) * 8;
            bf16x8 bh = *(const bf16x8*)(w3fh + woff);
            #pragma unroll
            for (int rt = 0; rt < 8; ++rt)
                acc3[rt][ctl] = MFMA16(af[rt], bh, acc3[rt][ctl]);
        }
    }
    // BN2 + ReLU; attn2 score partials
    float uv[4];
    {
        #pragma unroll
        for (int ctl = 0; ctl < 4; ++ctl) {
            int ch = (wv * 4 + ctl) * 16 + r;
            float s = sc2[ch], sh = sh2[ch];
            uv[ctl] = u[ch];
            #pragma unroll
            for (int rt = 0; rt < 8; ++rt)
                #pragma unroll
                for (int j = 0; j < 4; ++j)
                    acc3[rt][ctl][j] = fmaxf(acc3[rt][ctl][j] * s + sh, 0.f);
        }
        #pragma unroll
        for (int rt = 0; rt < 8; ++rt)
            #pragma unroll
            for (int j = 0; j < 4; ++j) {
                float s = uv[0] * acc3[rt][0][j] + uv[1] * acc3[rt][1][j]
                        + uv[2] * acc3[rt][2][j] + uv[3] * acc3[rt][3][j];
                s += __shfl_xor(s, 1); s += __shfl_xor(s, 2);
                s += __shfl_xor(s, 4); s += __shfl_xor(s, 8);
                if (r == 0) atomicAdd(&scs[rt * 16 + q * 4 + j], s);
            }
    }
    __syncthreads();

    // P8: wave-parallel softmax2
    if (wv < 4 && lane < 32) {
        float s = scs[wv * 32 + lane];
        float mx = s;
        mx = fmaxf(mx, __shfl_xor(mx, 16));
        mx = fmaxf(mx, __shfl_xor(mx, 8));
        mx = fmaxf(mx, __shfl_xor(mx, 4));
        mx = fmaxf(mx, __shfl_xor(mx, 2));
        mx = fmaxf(mx, __shfl_xor(mx, 1));
        float e = expf(s - mx);
        float sum = e;
        sum += __shfl_xor(sum, 16);
        sum += __shfl_xor(sum, 8);
        sum += __shfl_xor(sum, 4);
        sum += __shfl_xor(sum, 2);
        sum += __shfl_xor(sum, 1);
        sms[wv * 32 + lane] = e / sum;
    }
    __syncthreads();

    // P9: y[g][ch] = sum_k s[k]*x4[k][ch] -> global bf16
    {
        #pragma unroll
        for (int ctl = 0; ctl < 4; ++ctl)
            #pragma unroll
            for (int gg = 0; gg < 4; ++gg) {
                float p = 0.f;
                #pragma unroll
                for (int rr = 0; rr < 2; ++rr) {
                    int rt = gg * 2 + rr;
                    #pragma unroll
                    for (int j = 0; j < 4; ++j)
                        p += sms[rt * 16 + q * 4 + j] * acc3[rt][ctl][j];
                }
                p += __shfl_xor(p, 16);
                p += __shfl_xor(p, 32);
                if (q == 0) {
                    int grow = gb + gg;
                    int ch = (wv * 4 + ctl) * 16 + r;
                    yh[(size_t)grow * 512 + ch] = f2bf(p);
                }
            }
    }
}

// ---------------- fg2 GEMM: out = bb + y @ MT (hi-only) ----------------------
__global__ __launch_bounds__(256) void fg2_kernel(
    const short* __restrict__ yh,
    const short* __restrict__ MTfh,
    const float* __restrict__ bb, float* __restrict__ out_fg2)
{
    int gbase = blockIdx.x * 16;
    int t = threadIdx.x;
    int lane = t & 63, wv = t >> 6, q = lane >> 4, r = lane & 15;
    f32x4 acc[8];
    #pragma unroll
    for (int ctl = 0; ctl < 8; ++ctl) {
        float bv = bb[(wv * 8 + ctl) * 16 + r];
        acc[ctl] = (f32x4){bv, bv, bv, bv};
    }
    #pragma unroll
    for (int ks = 0; ks < 16; ++ks) {
        bf16x8 af = *(const bf16x8*)(yh + (size_t)(gbase + r) * 512 + ks * 32 + q * 8);
        #pragma unroll
        for (int ctl = 0; ctl < 8; ++ctl) {
            int ct = wv * 8 + ctl;
            size_t woff = ((size_t)(ct * 16 + ks) * 64 + lane) * 8;
            bf16x8 bh = *(const bf16x8*)(MTfh + woff);
            acc[ctl] = MFMA16(af, bh, acc[ctl]);
        }
    }
    #pragma unroll
    for (int ctl = 0; ctl < 8; ++ctl) {
        int ch = (wv * 8 + ctl) * 16 + r;
        #pragma unroll
        for (int j = 0; j < 4; ++j) {
            int grow = gbase + q * 4 + j;
            out_fg2[(size_t)grow * 512 + ch] = acc[ctl][j];
        }
    }
}

extern "C" void kernel_launch(void* const* d_in, const int* in_sizes, int n_in,
                              void* d_out, int out_size, void* d_ws, size_t ws_size,
                              hipStream_t stream) {
    const float* xyz  = (const float*)d_in[0];
    const int*   cidx = (const int*)d_in[1];
    const float* w1   = (const float*)d_in[2];
    const float* b1   = (const float*)d_in[3];
    const float* g1   = (const float*)d_in[4];
    const float* be1  = (const float*)d_in[5];
    const float* m1   = (const float*)d_in[6];
    const float* v1   = (const float*)d_in[7];
    const float* w2   = (const float*)d_in[8];
    const float* b2   = (const float*)d_in[9];
    const float* sw1  = (const float*)d_in[10];
    const float* sb1  = (const float*)d_in[11];
    const float* mw1  = (const float*)d_in[12];
    const float* mb1  = (const float*)d_in[13];
    const float* w3   = (const float*)d_in[14];
    const float* b3   = (const float*)d_in[15];
    const float* g2   = (const float*)d_in[16];
    const float* be2  = (const float*)d_in[17];
    const float* m2   = (const float*)d_in[18];
    const float* v2   = (const float*)d_in[19];
    const float* w4   = (const float*)d_in[20];
    const float* b4   = (const float*)d_in[21];
    const float* sw2  = (const float*)d_in[22];
    const float* sb2  = (const float*)d_in[23];
    const float* mw2  = (const float*)d_in[24];
    const float* mb2  = (const float*)d_in[25];

    float* out = (float*)d_out;
    char* ws = (char*)d_ws;
    short* w2fh = (short*)(ws + 524288);         // 65536
    short* w3fh = (short*)(ws + 655360);         // 262144
    short* Pfh  = (short*)(ws + 1179648);        // 262144
    short* w1fh = (short*)(ws + 1441792);        // 8192
    float* bc3  = (float*)(ws + 1703936);        // 2048
    float* sc1  = (float*)(ws + 1705984);        // 512
    float* shb1 = (float*)(ws + 1706496);        // 512
    float* sc2  = (float*)(ws + 1707008);        // 2048
    float* sh2  = (float*)(ws + 1709056);        // 2048
    float* u    = (float*)(ws + 1711104);        // 2048
    float* bb   = (float*)(ws + 1713152);        // 2048
    float* ub   = (float*)(ws + 1715200);        // 256 (pad)
    short* MTfh = (short*)(ws + 1715456);        // 524288
    short* yh   = (short*)(ws + 2764032);        // 4194304

    prep_kernel<<<1027, 256, 0, stream>>>(w1, b1, w2, w3, mw1, mw2, w4, b4,
                                          sw2, sb2, mb2, mb1, b3,
                                          g1, be1, m1, v1, g2, be2, m2, v2,
                                          w1fh, w2fh, w3fh, Pfh, MTfh,
                                          sc1, shb1, sc2, sh2, u, bb, ub, bc3);
    mlp_kernel<<<1024, 512, 0, stream>>>(xyz, cidx, out,
                                         w1fh, sc1, shb1, w2fh, b2,
                                         sw1, sb1, Pfh, bc3, w3fh,
                                         sc2, sh2, u, ub, yh);
    fg2_kernel<<<256, 256, 0, stream>>>(yh, MTfh, bb, out + 12288);
}

// Round 10
// 333.661 us; speedup vs baseline: 2.6159x; 2.0648x over previous
//
#include <hip/hip_runtime.h>
#include <math.h>

#define EPSV 1e-5f

typedef __attribute__((ext_vector_type(8))) short bf16x8;
typedef __attribute__((ext_vector_type(4))) float f32x4;

#define MFMA16(a, b, c) __builtin_amdgcn_mfma_f32_16x16x32_bf16(a, b, c, 0, 0, 0)

__device__ __forceinline__ short f2bf(float x) {
    unsigned u = __float_as_uint(x);
    unsigned r = (u + 0x7fffu + ((u >> 16) & 1u)) >> 16;
    return (short)r;
}
__device__ __forceinline__ float bf2f(short h) {
    return __uint_as_float(((unsigned)(unsigned short)h) << 16);
}
__device__ __forceinline__ void bsplit(float x, short& h, short& l) {
    h = f2bf(x);
    l = f2bf(x - bf2f(h));
}
__device__ __forceinline__ unsigned pack2(short a, short b) {
    return ((unsigned)(unsigned short)a) | (((unsigned)(unsigned short)b) << 16);
}

// ============ fused prep + KNN: one launch, roles by blockIdx ================
// KNN stays in its own high-occupancy blocks (256 thr, 12KB LDS -> 8 blocks/CU)
#define KCAP 2048
__global__ __launch_bounds__(256) void prep_knn(
    const float* __restrict__ xyz, const int* __restrict__ cidx,
    int* __restrict__ knn_idx, float* __restrict__ out_center,
    const float* __restrict__ w1, const float* __restrict__ b1,
    const float* __restrict__ w2, const float* __restrict__ w3,
    const float* __restrict__ mw1, const float* __restrict__ mw2,
    const float* __restrict__ w4, const float* __restrict__ b4,
    const float* __restrict__ sw2, const float* __restrict__ sb2,
    const float* __restrict__ mb2, const float* __restrict__ mb1,
    const float* __restrict__ b3,
    const float* __restrict__ g1, const float* __restrict__ be1,
    const float* __restrict__ m1, const float* __restrict__ v1,
    const float* __restrict__ g2, const float* __restrict__ be2,
    const float* __restrict__ m2, const float* __restrict__ v2,
    short* __restrict__ w1fh, short* __restrict__ w2fh, short* __restrict__ w3fh,
    short* __restrict__ Pfh, short* __restrict__ MTfh,
    float* __restrict__ sc1, float* __restrict__ shb1,
    float* __restrict__ sc2, float* __restrict__ sh2,
    float* __restrict__ u, float* __restrict__ bb, float* __restrict__ ub,
    float* __restrict__ bc3)
{
    __shared__ __align__(16) char shm[12416];
    int B = blockIdx.x, t = threadIdx.x;
    int lane = t & 63, w = t >> 6;

    if (B < 4096) {
        // ---------------- KNN (one group per block) ----------------
        unsigned* cu = (unsigned*)shm;                       // 8192B
        unsigned short* cix = (unsigned short*)(shm + 8192); // 4096B
        unsigned* Tws = (unsigned*)(shm + 12288);            // 16B
        unsigned* cntS = (unsigned*)(shm + 12304);
        int g = B, b = g >> 9;
        const float* xb = xyz + (size_t)b * 8192 * 3;
        int ci = cidx[g];
        float cx = xb[ci * 3 + 0], cy = xb[ci * 3 + 1], cz = xb[ci * 3 + 2];
        float c2 = cx * cx + cy * cy + cz * cz;
        if (t < 3) out_center[g * 3 + t] = xb[ci * 3 + t];
        if (t == 0) *cntS = 0;

        const float4* p4 = (const float4*)xb + (size_t)t * 24;
        unsigned ue[32];
        unsigned vmin = 0xffffffffu;
        #pragma unroll
        for (int ii = 0; ii < 8; ++ii) {
            float4 v0 = p4[ii * 3 + 0];
            float4 v1 = p4[ii * 3 + 1];
            float4 v2 = p4[ii * 3 + 2];
            float px[4], py[4], pz[4];
            px[0] = v0.x; py[0] = v0.y; pz[0] = v0.z;
            px[1] = v0.w; py[1] = v1.x; pz[1] = v1.y;
            px[2] = v1.z; py[2] = v1.w; pz[2] = v2.x;
            px[3] = v2.y; py[3] = v2.z; pz[3] = v2.w;
            #pragma unroll
            for (int m = 0; m < 4; ++m) {
                float dx = px[m], dy = py[m], dz = pz[m];
                float n2 = dx * dx + dy * dy + dz * dz;
                float d = c2 + n2 - 2.f * (cx * dx + cy * dy + cz * dz);
                unsigned uu = __float_as_uint(d);
                uu = (uu & 0x80000000u) ? ~uu : (uu | 0x80000000u);
                ue[ii * 4 + m] = uu;
                vmin = min(vmin, uu);
            }
        }
        unsigned v = vmin;
        #pragma unroll
        for (int k = 2; k <= 64; k <<= 1) {
            #pragma unroll
            for (int jj = k >> 1; jj > 0; jj >>= 1) {
                unsigned o = __shfl_xor(v, jj);
                bool dir_asc = ((lane & k) == 0) || (k == 64);
                bool lower = (lane & jj) == 0;
                bool take_min = (lower == dir_asc);
                unsigned mn = min(v, o), mx = max(v, o);
                v = take_min ? mn : mx;
            }
        }
        unsigned Tw = __shfl(v, 31);
        if (lane == 0) Tws[w] = Tw;
        __syncthreads();
        unsigned T = min(min(Tws[0], Tws[1]), min(Tws[2], Tws[3]));
        #pragma unroll
        for (int i = 0; i < 32; ++i) {
            if (ue[i] <= T) {
                unsigned pos = atomicAdd(cntS, 1u);
                if (pos < KCAP) {
                    cu[pos] = ue[i];
                    cix[pos] = (unsigned short)(t * 32 + i);
                }
            }
        }
        __syncthreads();
        int C = (int)min(*cntS, (unsigned)KCAP);
        for (int cc = t; cc < C; cc += 256) {
            unsigned uc = cu[cc];
            unsigned short icd = cix[cc];
            int rank = 0;
            for (int j = 0; j < C; ++j) {
                unsigned uj = cu[j];
                rank += (uj < uc) || (uj == uc && cix[j] < icd);
            }
            if (rank < 32) knn_idx[g * 32 + rank] = (int)icd;
        }
        return;
    }

    if (B < 4352) {
        // prep_P: P[c][o] = sum_d mw1[d][c]*w3[o][d]  (hi only)
        float* col = (float*)shm;
        int c = B - 4096;
        col[t] = mw1[t * 256 + c];
        __syncthreads();
        int ks = c >> 5, qq = (c >> 3) & 3, jj = c & 7;
        for (int oo = t; oo < 512; oo += 256) {
            float acc = 0.f;
            for (int d = 0; d < 256; ++d) acc += col[d] * w3[oo * 512 + d];
            int ct = oo >> 4;
            size_t idx = ((size_t)(ct * 8 + ks) * 64 + qq * 16 + (oo & 15)) * 8 + jj;
            Pfh[idx] = f2bf(acc);
        }
        return;
    }

    if (B < 4864) {
        // prep_MT + pack (hi only)
        float* row = (float*)shm;
        int qq = B - 4352;
        row[t] = mw2[(size_t)qq * 512 + t];
        row[t + 256] = mw2[(size_t)qq * 512 + t + 256];
        __syncthreads();
        float a0 = 0.f, a1 = 0.f;
        for (int o = 0; o < 512; ++o) {
            float m = row[o];
            a0 += m * w4[o * 512 + t];
            a1 += m * w4[o * 512 + t + 256];
        }
        int ct = qq >> 4, nl = qq & 15;
        {
            int k = t;
            size_t i0 = (((size_t)(ct * 16 + (k >> 5))) << 9)
                      | ((((k >> 3) & 3) * 16 + nl) << 3) | (k & 7);
            MTfh[i0] = f2bf(a0);
        }
        {
            int k = t + 256;
            size_t i1 = (((size_t)(ct * 16 + (k >> 5))) << 9)
                      | ((((k >> 3) & 3) * 16 + nl) << 3) | (k & 7);
            MTfh[i1] = f2bf(a1);
        }
        return;
    }

    if (B < 4992) {
        // w2/w3 fragment packing (hi only)
        int tid = (B - 4864) * 256 + t;
        {
            int i = tid;
            int j = i & 7, ln = (i >> 3) & 63, rest = i >> 9;
            int ks = rest & 3, ct = rest >> 2;
            int o = ct * 16 + (ln & 15);
            int k = ks * 32 + (ln >> 4) * 8 + j;
            w2fh[i] = f2bf(w2[o * 128 + k]);
        }
        #pragma unroll
        for (int s = 0; s < 4; ++s) {
            int i = tid + s * 32768;
            int j = i & 7, ln = (i >> 3) & 63, rest = i >> 9;
            int ks = rest & 7, ct = rest >> 3;
            int o = ct * 16 + (ln & 15);
            int c = 256 + ks * 32 + (ln >> 4) * 8 + j;
            w3fh[i] = f2bf(w3[o * 512 + c]);
        }
        return;
    }

    if (B < 5056) {
        float* b4s = (float*)shm;
        float* red = (float*)(shm + 2048);
        b4s[t] = b4[t];
        b4s[t + 256] = b4[t + 256];
        __syncthreads();
        int q0 = (B - 4992) * 8;
        for (int i = 0; i < 8; ++i) {
            int q = q0 + i;
            float part = mw2[(size_t)q * 512 + t] * b4s[t]
                       + mw2[(size_t)q * 512 + 256 + t] * b4s[256 + t];
            #pragma unroll
            for (int off = 32; off > 0; off >>= 1) part += __shfl_down(part, off);
            if (lane == 0) red[w] = part;
            __syncthreads();
            if (t == 0) bb[q] = mb2[q] + red[0] + red[1] + red[2] + red[3];
            __syncthreads();
        }
        return;
    }

    if (B < 5120) {
        float* mb1s = (float*)shm;
        float* red = (float*)(shm + 1024);
        mb1s[t] = mb1[t];
        __syncthreads();
        int o0 = (B - 5056) * 8;
        for (int i = 0; i < 8; ++i) {
            int o = o0 + i;
            float part = w3[(size_t)o * 512 + t] * mb1s[t];
            #pragma unroll
            for (int off = 32; off > 0; off >>= 1) part += __shfl_down(part, off);
            if (lane == 0) red[w] = part;
            __syncthreads();
            if (t == 0) bc3[o] = b3[o] + red[0] + red[1] + red[2] + red[3];
            __syncthreads();
        }
        return;
    }

    if (B < 5122) {
        int c = (B - 5120) * 256 + t;
        float acc = 0.f;
        for (int o = 0; o < 512; ++o) acc += sw2[o] * w4[o * 512 + c];
        u[c] = acc;
        return;
    }

    // scales + shb1 + w1 frags + ub
    if (t < 128) {
        float s = g1[t] * rsqrtf(v1[t] + EPSV);
        float sh = be1[t] - m1[t] * s;
        sc1[t] = s;
        shb1[t] = b1[t] * s + sh;
    }
    {
        float s = g2[t] * rsqrtf(v2[t] + EPSV);
        sc2[t] = s; sh2[t] = be2[t] - m2[t] * s;
        s = g2[t + 256] * rsqrtf(v2[t + 256] + EPSV);
        sc2[t + 256] = s; sh2[t + 256] = be2[t + 256] - m2[t + 256] * s;
    }
    #pragma unroll
    for (int s = 0; s < 16; ++s) {
        int i = t + s * 256;
        int j = i & 7, ln = (i >> 3) & 63, ct = i >> 9;
        int o = ct * 16 + (ln & 15);
        int k = (ln >> 4) * 8 + j;
        w1fh[i] = (k < 10) ? f2bf(w1[o * 10 + k]) : (short)0;
    }
    if (t < 64) {
        float part = 0.f;
        #pragma unroll
        for (int i = 0; i < 8; ++i) part += sw2[t * 8 + i] * b4[t * 8 + i];
        #pragma unroll
        for (int off = 32; off > 0; off >>= 1) part += __shfl_down(part, off);
        if (t == 0) ub[0] = sb2[0] + part;
    }
}

// ---------------- fused per-group MLP (4 groups/block, 512 threads) ----------
__global__ __launch_bounds__(512) void mlp_kernel(
    const float* __restrict__ xyz, const int* __restrict__ cidx,
    const int* __restrict__ knn_idx,
    const short* __restrict__ w1fh,
    const float* __restrict__ sc1, const float* __restrict__ shb1,
    const short* __restrict__ w2fh,
    const float* __restrict__ b2,
    const float* __restrict__ sw1, const float* __restrict__ sb1,
    const short* __restrict__ Pfh, const float* __restrict__ bc3,
    const short* __restrict__ w3fh,
    const float* __restrict__ sc2, const float* __restrict__ sh2,
    const float* __restrict__ u, const float* __restrict__ ubp,
    short* __restrict__ yh)
{
    __shared__ __align__(16) char smem[70656];
    short* x1 = (short*)smem;                    // [128][128] bf16 swizzled
    short* x2 = (short*)smem;                    // [128][256] bf16 swizzled (overlays x1)
    short* feat = (short*)(smem + 32768);        // [128][40]: h c0-15, l c16-31 (10240B; dead before x2 store)
    short* poolA = (short*)(smem + 65536);       // [8][256] bf16 swizzled, 4KB
    float* scs = (float*)(smem + 69632);         // [128]
    float* sms = (float*)(smem + 70144);         // [128]

    int gb = blockIdx.x * 4;
    int bq = gb >> 9;
    int t = threadIdx.x;
    int lane = t & 63, wv = t >> 6, q = lane >> 4, r = lane & 15;
    const float* xb = xyz + (size_t)bq * 8192 * 3;

    // P1: feat gather -> feat [128][40] (80B row stride: 2-way bank alias, free)
    if (t < 128) {
        int gg = t >> 5;
        int ci = cidx[gb + gg];
        float cxx = xb[ci * 3 + 0], cyy = xb[ci * 3 + 1], czz = xb[ci * 3 + 2];
        int n = knn_idx[(gb + gg) * 32 + (t & 31)];
        float nx = xb[n * 3 + 0], ny = xb[n * 3 + 1], nz = xb[n * 3 + 2];
        float rx = cxx - nx, ry = cyy - ny, rz = czz - nz;
        float rd = sqrtf(rx * rx + ry * ry + rz * rz);
        float f[10];
        f[0] = rd; f[1] = rx; f[2] = ry; f[3] = rz;
        f[4] = cxx; f[5] = cyy; f[6] = czz;
        f[7] = nx; f[8] = ny; f[9] = nz;
        unsigned* fr = (unsigned*)(feat + t * 40);
        short h0, l0, h1, l1;
        #pragma unroll
        for (int c = 0; c < 10; c += 2) {
            bsplit(f[c], h0, l0);
            bsplit(f[c + 1], h1, l1);
            fr[c >> 1] = pack2(h0, h1);
            fr[8 + (c >> 1)] = pack2(l0, l1);
        }
        fr[5] = 0; fr[6] = 0; fr[7] = 0;
        fr[13] = 0; fr[14] = 0; fr[15] = 0;
    }
    if (t < 128) scs[t] = sb1[0];
    __syncthreads();

    // P2: conv1 via MFMA: M=128, N=128 (wave: 1 ct), K=32 (10 real)
    {
        f32x4 acc1[8];
        #pragma unroll
        for (int rt = 0; rt < 8; ++rt) acc1[rt] = (f32x4){0.f, 0.f, 0.f, 0.f};
        bf16x8 bw = *(const bf16x8*)(w1fh + ((size_t)wv * 64 + lane) * 8);
        bf16x8 zerov = (bf16x8){0, 0, 0, 0, 0, 0, 0, 0};
        #pragma unroll
        for (int rt = 0; rt < 8; ++rt) {
            int row = rt * 16 + r;
            bf16x8 ah = zerov, al = zerov;
            if (q < 2) {
                ah = *(const bf16x8*)(feat + row * 40 + q * 8);
                al = *(const bf16x8*)(feat + row * 40 + 16 + q * 8);
            }
            acc1[rt] = MFMA16(al, bw, acc1[rt]);
            acc1[rt] = MFMA16(ah, bw, acc1[rt]);
        }
        int o = wv * 16 + r;
        float s1v = sc1[o], sbv = shb1[o];
        #pragma unroll
        for (int rt = 0; rt < 8; ++rt)
            #pragma unroll
            for (int j = 0; j < 4; ++j) {
                int row = rt * 16 + q * 4 + j;
                float vv = fmaxf(acc1[rt][j] * s1v + sbv, 0.f);
                x1[row * 128 + (o ^ ((row & 7) << 3))] = f2bf(vv);
            }
    }
    __syncthreads();

    // P3: conv2 via MFMA (hi weights): M=128, N=256 (wave: 2 ct), K=128
    f32x4 acc2[8][2];
    #pragma unroll
    for (int rt = 0; rt < 8; ++rt)
        #pragma unroll
        for (int ctl = 0; ctl < 2; ++ctl) {
            float bv = b2[(wv * 2 + ctl) * 16 + r];
            acc2[rt][ctl] = (f32x4){bv, bv, bv, bv};
        }
    #pragma unroll
    for (int ks = 0; ks < 4; ++ks) {
        bf16x8 af[8];
        #pragma unroll
        for (int rt = 0; rt < 8; ++rt) {
            int row = rt * 16 + r;
            int kk = ks * 32 + q * 8;
            af[rt] = *(const bf16x8*)(x1 + row * 128 + (kk ^ ((row & 7) << 3)));
        }
        #pragma unroll
        for (int ctl = 0; ctl < 2; ++ctl) {
            int ct = wv * 2 + ctl;
            size_t woff = ((size_t)(ct * 4 + ks) * 64 + lane) * 8;
            bf16x8 bh = *(const bf16x8*)(w2fh + woff);
            #pragma unroll
            for (int rt = 0; rt < 8; ++rt)
                acc2[rt][ctl] = MFMA16(af[rt], bh, acc2[rt][ctl]);
        }
    }
    // attn1 score partials
    {
        float sw1v[2];
        #pragma unroll
        for (int ctl = 0; ctl < 2; ++ctl) sw1v[ctl] = sw1[(wv * 2 + ctl) * 16 + r];
        #pragma unroll
        for (int rt = 0; rt < 8; ++rt)
            #pragma unroll
            for (int j = 0; j < 4; ++j) {
                float s = sw1v[0] * acc2[rt][0][j] + sw1v[1] * acc2[rt][1][j];
                s += __shfl_xor(s, 1); s += __shfl_xor(s, 2);
                s += __shfl_xor(s, 4); s += __shfl_xor(s, 8);
                if (r == 0) atomicAdd(&scs[rt * 16 + q * 4 + j], s);
            }
    }
    __syncthreads();

    // P4: wave-parallel softmax1 + x2 store
    if (wv < 4 && lane < 32) {
        float s = scs[wv * 32 + lane];
        float mx = s;
        mx = fmaxf(mx, __shfl_xor(mx, 16));
        mx = fmaxf(mx, __shfl_xor(mx, 8));
        mx = fmaxf(mx, __shfl_xor(mx, 4));
        mx = fmaxf(mx, __shfl_xor(mx, 2));
        mx = fmaxf(mx, __shfl_xor(mx, 1));
        float e = expf(s - mx);
        float sum = e;
        sum += __shfl_xor(sum, 16);
        sum += __shfl_xor(sum, 8);
        sum += __shfl_xor(sum, 4);
        sum += __shfl_xor(sum, 2);
        sum += __shfl_xor(sum, 1);
        sms[wv * 32 + lane] = e / sum;
    }
    #pragma unroll
    for (int rt = 0; rt < 8; ++rt)
        #pragma unroll
        for (int ctl = 0; ctl < 2; ++ctl) {
            int ch = (wv * 2 + ctl) * 16 + r;
            #pragma unroll
            for (int j = 0; j < 4; ++j) {
                int row = rt * 16 + q * 4 + j;
                x2[row * 256 + (ch ^ ((row & 7) << 3))] = f2bf(acc2[rt][ctl][j]);
            }
        }
    __syncthreads();

    // P5: pool1 -> poolA bf16 rows (hi: gg, lo: gg+4); scs re-init for attn2
    {
        #pragma unroll
        for (int ctl = 0; ctl < 2; ++ctl)
            #pragma unroll
            for (int gg = 0; gg < 4; ++gg) {
                float p = 0.f;
                #pragma unroll
                for (int rr = 0; rr < 2; ++rr) {
                    int rt = gg * 2 + rr;
                    #pragma unroll
                    for (int j = 0; j < 4; ++j)
                        p += sms[rt * 16 + q * 4 + j] * acc2[rt][ctl][j];
                }
                p += __shfl_xor(p, 16);
                p += __shfl_xor(p, 32);
                if (q == 0) {
                    int ch = (wv * 2 + ctl) * 16 + r;
                    short h, l; bsplit(p, h, l);
                    poolA[gg * 256 + (ch ^ (gg << 3))] = h;
                    poolA[(gg + 4) * 256 + (ch ^ ((gg + 4) << 3))] = l;
                }
            }
        if (t < 128) scs[t] = ubp[0];
    }
    __syncthreads();

    // P6: pool@P via MFMA (registers only; A rows 0-7 = poolA hi/lo, 8-15 zero)
    float fgv[4][4];   // [ctl][group]
    float bc3v[4];
    {
        f32x4 accP[4];
        #pragma unroll
        for (int ctl = 0; ctl < 4; ++ctl) accP[ctl] = (f32x4){0.f, 0.f, 0.f, 0.f};
        #pragma unroll
        for (int ks = 0; ks < 8; ++ks) {
            int kk = ks * 32 + q * 8;
            bf16x8 pa;
            if (r < 8) pa = *(const bf16x8*)(poolA + r * 256 + (kk ^ (r << 3)));
            else pa = (bf16x8){0, 0, 0, 0, 0, 0, 0, 0};
            #pragma unroll
            for (int ctl = 0; ctl < 4; ++ctl) {
                size_t woff = ((size_t)((wv * 4 + ctl) * 8 + ks) * 64 + lane) * 8;
                bf16x8 ph = *(const bf16x8*)(Pfh + woff);
                accP[ctl] = MFMA16(pa, ph, accP[ctl]);
            }
        }
        #pragma unroll
        for (int ctl = 0; ctl < 4; ++ctl) {
            bc3v[ctl] = bc3[(wv * 4 + ctl) * 16 + r];
            #pragma unroll
            for (int j = 0; j < 4; ++j) {
                float x = accP[ctl][j];
                x += __shfl_xor(x, 16);
                x += __shfl_xor(x, 32);
                fgv[ctl][j] = x;
            }
        }
    }

    // P7: conv3 via MFMA (hi weights): M=128, N=512, K=256; init = fgv + bc3
    f32x4 acc3[8][4];
    #pragma unroll
    for (int rt = 0; rt < 8; ++rt) {
        int gg = rt >> 1;
        #pragma unroll
        for (int ctl = 0; ctl < 4; ++ctl) {
            float fp = fgv[ctl][gg] + bc3v[ctl];
            acc3[rt][ctl] = (f32x4){fp, fp, fp, fp};
        }
    }
    #pragma unroll
    for (int ks = 0; ks < 8; ++ks) {
        bf16x8 af[8];
        #pragma unroll
        for (int rt = 0; rt < 8; ++rt) {
            int row = rt * 16 + r;
            int kk = ks * 32 + q * 8;
            af[rt] = *(const bf16x8*)(x2 + row * 256 + (kk ^ ((row & 7) << 3)));
        }
        #pragma unroll
        for (int ctl = 0; ctl < 4; ++ctl) {
            int ct = wv * 4 + ctl;
            size_t woff = ((size_t)(ct * 8 + ks) * 64 + lane) * 8;
            bf16x8 bh = *(const bf16x8*)(w3fh + woff);
            #pragma unroll
            for (int rt = 0; rt < 8; ++rt)
                acc3[rt][ctl] = MFMA16(af[rt], bh, acc3[rt][ctl]);
        }
    }
    // BN2 + ReLU; attn2 score partials
    float uv[4];
    {
        #pragma unroll
        for (int ctl = 0; ctl < 4; ++ctl) {
            int ch = (wv * 4 + ctl) * 16 + r;
            float s = sc2[ch], sh = sh2[ch];
            uv[ctl] = u[ch];
            #pragma unroll
            for (int rt = 0; rt < 8; ++rt)
                #pragma unroll
                for (int j = 0; j < 4; ++j)
                    acc3[rt][ctl][j] = fmaxf(acc3[rt][ctl][j] * s + sh, 0.f);
        }
        #pragma unroll
        for (int rt = 0; rt < 8; ++rt)
            #pragma unroll
            for (int j = 0; j < 4; ++j) {
                float s = uv[0] * acc3[rt][0][j] + uv[1] * acc3[rt][1][j]
                        + uv[2] * acc3[rt][2][j] + uv[3] * acc3[rt][3][j];
                s += __shfl_xor(s, 1); s += __shfl_xor(s, 2);
                s += __shfl_xor(s, 4); s += __shfl_xor(s, 8);
                if (r == 0) atomicAdd(&scs[rt * 16 + q * 4 + j], s);
            }
    }
    __syncthreads();

    // P8: wave-parallel softmax2
    if (wv < 4 && lane < 32) {
        float s = scs[wv * 32 + lane];
        float mx = s;
        mx = fmaxf(mx, __shfl_xor(mx, 16));
        mx = fmaxf(mx, __shfl_xor(mx, 8));
        mx = fmaxf(mx, __shfl_xor(mx, 4));
        mx = fmaxf(mx, __shfl_xor(mx, 2));
        mx = fmaxf(mx, __shfl_xor(mx, 1));
        float e = expf(s - mx);
        float sum = e;
        sum += __shfl_xor(sum, 16);
        sum += __shfl_xor(sum, 8);
        sum += __shfl_xor(sum, 4);
        sum += __shfl_xor(sum, 2);
        sum += __shfl_xor(sum, 1);
        sms[wv * 32 + lane] = e / sum;
    }
    __syncthreads();

    // P9: y[g][ch] = sum_k s[k]*x4[k][ch] -> global bf16
    {
        #pragma unroll
        for (int ctl = 0; ctl < 4; ++ctl)
            #pragma unroll
            for (int gg = 0; gg < 4; ++gg) {
                float p = 0.f;
                #pragma unroll
                for (int rr = 0; rr < 2; ++rr) {
                    int rt = gg * 2 + rr;
                    #pragma unroll
                    for (int j = 0; j < 4; ++j)
                        p += sms[rt * 16 + q * 4 + j] * acc3[rt][ctl][j];
                }
                p += __shfl_xor(p, 16);
                p += __shfl_xor(p, 32);
                if (q == 0) {
                    int grow = gb + gg;
                    int ch = (wv * 4 + ctl) * 16 + r;
                    yh[(size_t)grow * 512 + ch] = f2bf(p);
                }
            }
    }
}

// ---------------- fg2 GEMM: out = bb + y @ MT (hi-only) ----------------------
__global__ __launch_bounds__(256) void fg2_kernel(
    const short* __restrict__ yh,
    const short* __restrict__ MTfh,
    const float* __restrict__ bb, float* __restrict__ out_fg2)
{
    int gbase = blockIdx.x * 16;
    int t = threadIdx.x;
    int lane = t & 63, wv = t >> 6, q = lane >> 4, r = lane & 15;
    f32x4 acc[8];
    #pragma unroll
    for (int ctl = 0; ctl < 8; ++ctl) {
        float bv = bb[(wv * 8 + ctl) * 16 + r];
        acc[ctl] = (f32x4){bv, bv, bv, bv};
    }
    #pragma unroll
    for (int ks = 0; ks < 16; ++ks) {
        bf16x8 af = *(const bf16x8*)(yh + (size_t)(gbase + r) * 512 + ks * 32 + q * 8);
        #pragma unroll
        for (int ctl = 0; ctl < 8; ++ctl) {
            int ct = wv * 8 + ctl;
            size_t woff = ((size_t)(ct * 16 + ks) * 64 + lane) * 8;
            bf16x8 bh = *(const bf16x8*)(MTfh + woff);
            acc[ctl] = MFMA16(af, bh, acc[ctl]);
        }
    }
    #pragma unroll
    for (int ctl = 0; ctl < 8; ++ctl) {
        int ch = (wv * 8 + ctl) * 16 + r;
        #pragma unroll
        for (int j = 0; j < 4; ++j) {
            int grow = gbase + q * 4 + j;
            out_fg2[(size_t)grow * 512 + ch] = acc[ctl][j];
        }
    }
}

extern "C" void kernel_launch(void* const* d_in, const int* in_sizes, int n_in,
                              void* d_out, int out_size, void* d_ws, size_t ws_size,
                              hipStream_t stream) {
    const float* xyz  = (const float*)d_in[0];
    const int*   cidx = (const int*)d_in[1];
    const float* w1   = (const float*)d_in[2];
    const float* b1   = (const float*)d_in[3];
    const float* g1   = (const float*)d_in[4];
    const float* be1  = (const float*)d_in[5];
    const float* m1   = (const float*)d_in[6];
    const float* v1   = (const float*)d_in[7];
    const float* w2   = (const float*)d_in[8];
    const float* b2   = (const float*)d_in[9];
    const float* sw1  = (const float*)d_in[10];
    const float* sb1  = (const float*)d_in[11];
    const float* mw1  = (const float*)d_in[12];
    const float* mb1  = (const float*)d_in[13];
    const float* w3   = (const float*)d_in[14];
    const float* b3   = (const float*)d_in[15];
    const float* g2   = (const float*)d_in[16];
    const float* be2  = (const float*)d_in[17];
    const float* m2   = (const float*)d_in[18];
    const float* v2   = (const float*)d_in[19];
    const float* w4   = (const float*)d_in[20];
    const float* b4   = (const float*)d_in[21];
    const float* sw2  = (const float*)d_in[22];
    const float* sb2  = (const float*)d_in[23];
    const float* mw2  = (const float*)d_in[24];
    const float* mb2  = (const float*)d_in[25];

    float* out = (float*)d_out;
    char* ws = (char*)d_ws;
    int*   knn_idx = (int*)(ws + 0);             // 524288
    short* w2fh = (short*)(ws + 524288);         // 65536
    short* w3fh = (short*)(ws + 655360);         // 262144
    short* Pfh  = (short*)(ws + 1179648);        // 262144
    short* w1fh = (short*)(ws + 1441792);        // 8192
    float* bc3  = (float*)(ws + 1703936);        // 2048
    float* sc1  = (float*)(ws + 1705984);        // 512
    float* shb1 = (float*)(ws + 1706496);        // 512
    float* sc2  = (float*)(ws + 1707008);        // 2048
    float* sh2  = (float*)(ws + 1709056);        // 2048
    float* u    = (float*)(ws + 1711104);        // 2048
    float* bb   = (float*)(ws + 1713152);        // 2048
    float* ub   = (float*)(ws + 1715200);        // 256 (pad)
    short* MTfh = (short*)(ws + 1715456);        // 524288
    short* yh   = (short*)(ws + 2764032);        // 4194304

    prep_knn<<<5123, 256, 0, stream>>>(xyz, cidx, knn_idx, out,
                                       w1, b1, w2, w3, mw1, mw2, w4, b4, sw2, sb2,
                                       mb2, mb1, b3,
                                       g1, be1, m1, v1, g2, be2, m2, v2,
                                       w1fh, w2fh, w3fh, Pfh, MTfh,
                                       sc1, shb1, sc2, sh2, u, bb, ub, bc3);
    mlp_kernel<<<1024, 512, 0, stream>>>(xyz, cidx, knn_idx,
                                         w1fh, sc1, shb1, w2fh, b2,
                                         sw1, sb1, Pfh, bc3, w3fh,
                                         sc2, sh2, u, ub, yh);
    fg2_kernel<<<256, 256, 0, stream>>>(yh, MTfh, bb, out + 12288);
}

// Round 11
// 325.750 us; speedup vs baseline: 2.6794x; 1.0243x over previous
//
#include <hip/hip_runtime.h>
#include <math.h>

#define EPSV 1e-5f

typedef __attribute__((ext_vector_type(8))) short bf16x8;
typedef __attribute__((ext_vector_type(4))) float f32x4;

#define MFMA16(a, b, c) __builtin_amdgcn_mfma_f32_16x16x32_bf16(a, b, c, 0, 0, 0)

__device__ __forceinline__ short f2bf(float x) {
    unsigned u = __float_as_uint(x);
    unsigned r = (u + 0x7fffu + ((u >> 16) & 1u)) >> 16;
    return (short)r;
}
__device__ __forceinline__ float bf2f(short h) {
    return __uint_as_float(((unsigned)(unsigned short)h) << 16);
}
__device__ __forceinline__ void bsplit(float x, short& h, short& l) {
    h = f2bf(x);
    l = f2bf(x - bf2f(h));
}
__device__ __forceinline__ unsigned pack2(short a, short b) {
    return ((unsigned)(unsigned short)a) | (((unsigned)(unsigned short)b) << 16);
}
// HW packed f32->bf16 (RTNE): low16 = src0, high16 = src1
__device__ __forceinline__ unsigned cvtpk(float lo, float hi) {
    unsigned d;
    asm("v_cvt_pk_bf16_f32 %0, %1, %2" : "=v"(d) : "v"(lo), "v"(hi));
    return d;
}

// ============ fused prep + KNN: one launch, roles by blockIdx ================
#define KCAP 2048
__global__ __launch_bounds__(256) void prep_knn(
    const float* __restrict__ xyz, const int* __restrict__ cidx,
    int* __restrict__ knn_idx, float* __restrict__ out_center,
    const float* __restrict__ w1, const float* __restrict__ b1,
    const float* __restrict__ w2, const float* __restrict__ w3,
    const float* __restrict__ mw1, const float* __restrict__ mw2,
    const float* __restrict__ w4, const float* __restrict__ b4,
    const float* __restrict__ sw2, const float* __restrict__ sb2,
    const float* __restrict__ mb2, const float* __restrict__ mb1,
    const float* __restrict__ b3,
    const float* __restrict__ g1, const float* __restrict__ be1,
    const float* __restrict__ m1, const float* __restrict__ v1,
    const float* __restrict__ g2, const float* __restrict__ be2,
    const float* __restrict__ m2, const float* __restrict__ v2,
    short* __restrict__ w1fh, short* __restrict__ w2fh, short* __restrict__ w3fh,
    short* __restrict__ Pfh, short* __restrict__ MTfh,
    float* __restrict__ sc1, float* __restrict__ shb1,
    float* __restrict__ sc2, float* __restrict__ sh2,
    float* __restrict__ u, float* __restrict__ bb, float* __restrict__ ub,
    float* __restrict__ bc3)
{
    __shared__ __align__(16) char shm[12416];
    int B = blockIdx.x, t = threadIdx.x;
    int lane = t & 63, w = t >> 6;

    if (B < 4096) {
        // ---------------- KNN (one group per block) ----------------
        unsigned* cu = (unsigned*)shm;
        unsigned short* cix = (unsigned short*)(shm + 8192);
        unsigned* Tws = (unsigned*)(shm + 12288);
        unsigned* cntS = (unsigned*)(shm + 12304);
        int g = B, b = g >> 9;
        const float* xb = xyz + (size_t)b * 8192 * 3;
        int ci = cidx[g];
        float cx = xb[ci * 3 + 0], cy = xb[ci * 3 + 1], cz = xb[ci * 3 + 2];
        float c2 = cx * cx + cy * cy + cz * cz;
        if (t < 3) out_center[g * 3 + t] = xb[ci * 3 + t];
        if (t == 0) *cntS = 0;

        const float4* p4 = (const float4*)xb + (size_t)t * 24;
        unsigned ue[32];
        unsigned vmin = 0xffffffffu;
        #pragma unroll
        for (int ii = 0; ii < 8; ++ii) {
            float4 v0 = p4[ii * 3 + 0];
            float4 v1 = p4[ii * 3 + 1];
            float4 v2 = p4[ii * 3 + 2];
            float px[4], py[4], pz[4];
            px[0] = v0.x; py[0] = v0.y; pz[0] = v0.z;
            px[1] = v0.w; py[1] = v1.x; pz[1] = v1.y;
            px[2] = v1.z; py[2] = v1.w; pz[2] = v2.x;
            px[3] = v2.y; py[3] = v2.z; pz[3] = v2.w;
            #pragma unroll
            for (int m = 0; m < 4; ++m) {
                float dx = px[m], dy = py[m], dz = pz[m];
                float n2 = dx * dx + dy * dy + dz * dz;
                float d = c2 + n2 - 2.f * (cx * dx + cy * dy + cz * dz);
                unsigned uu = __float_as_uint(d);
                uu = (uu & 0x80000000u) ? ~uu : (uu | 0x80000000u);
                ue[ii * 4 + m] = uu;
                vmin = min(vmin, uu);
            }
        }
        unsigned v = vmin;
        #pragma unroll
        for (int k = 2; k <= 64; k <<= 1) {
            #pragma unroll
            for (int jj = k >> 1; jj > 0; jj >>= 1) {
                unsigned o = __shfl_xor(v, jj);
                bool dir_asc = ((lane & k) == 0) || (k == 64);
                bool lower = (lane & jj) == 0;
                bool take_min = (lower == dir_asc);
                unsigned mn = min(v, o), mx = max(v, o);
                v = take_min ? mn : mx;
            }
        }
        unsigned Tw = __shfl(v, 31);
        if (lane == 0) Tws[w] = Tw;
        __syncthreads();
        unsigned T = min(min(Tws[0], Tws[1]), min(Tws[2], Tws[3]));
        #pragma unroll
        for (int i = 0; i < 32; ++i) {
            if (ue[i] <= T) {
                unsigned pos = atomicAdd(cntS, 1u);
                if (pos < KCAP) {
                    cu[pos] = ue[i];
                    cix[pos] = (unsigned short)(t * 32 + i);
                }
            }
        }
        __syncthreads();
        int C = (int)min(*cntS, (unsigned)KCAP);
        for (int cc = t; cc < C; cc += 256) {
            unsigned uc = cu[cc];
            unsigned short icd = cix[cc];
            int rank = 0;
            for (int j = 0; j < C; ++j) {
                unsigned uj = cu[j];
                rank += (uj < uc) || (uj == uc && cix[j] < icd);
            }
            if (rank < 32) knn_idx[g * 32 + rank] = (int)icd;
        }
        return;
    }

    if (B < 4352) {
        // prep_P (hi only), interleaved-4 output channels:
        // fragment (ct, n) holds o = (ct>>2)*64 + 4n + (ct&3)
        float* col = (float*)shm;
        int c = B - 4096;
        col[t] = mw1[t * 256 + c];
        __syncthreads();
        int ks = c >> 5, qq = (c >> 3) & 3, jj = c & 7;
        for (int oo = t; oo < 512; oo += 256) {
            float acc = 0.f;
            for (int d = 0; d < 256; ++d) acc += col[d] * w3[oo * 512 + d];
            int ct = (oo >> 6) * 4 + (oo & 3);
            int n = (oo >> 2) & 15;
            size_t idx = ((size_t)(ct * 8 + ks) * 64 + qq * 16 + n) * 8 + jj;
            Pfh[idx] = f2bf(acc);
        }
        return;
    }

    if (B < 4864) {
        // prep_MT + pack (hi only) -- layout unchanged
        float* row = (float*)shm;
        int qq = B - 4352;
        row[t] = mw2[(size_t)qq * 512 + t];
        row[t + 256] = mw2[(size_t)qq * 512 + t + 256];
        __syncthreads();
        float a0 = 0.f, a1 = 0.f;
        for (int o = 0; o < 512; ++o) {
            float m = row[o];
            a0 += m * w4[o * 512 + t];
            a1 += m * w4[o * 512 + t + 256];
        }
        int ct = qq >> 4, nl = qq & 15;
        {
            int k = t;
            size_t i0 = (((size_t)(ct * 16 + (k >> 5))) << 9)
                      | ((((k >> 3) & 3) * 16 + nl) << 3) | (k & 7);
            MTfh[i0] = f2bf(a0);
        }
        {
            int k = t + 256;
            size_t i1 = (((size_t)(ct * 16 + (k >> 5))) << 9)
                      | ((((k >> 3) & 3) * 16 + nl) << 3) | (k & 7);
            MTfh[i1] = f2bf(a1);
        }
        return;
    }

    if (B < 4992) {
        // w2/w3 fragment packing (hi only), channel-interleaved
        int tid = (B - 4864) * 256 + t;
        {
            int i = tid;
            int j = i & 7, ln = (i >> 3) & 63, rest = i >> 9;
            int ks = rest & 3, ct = rest >> 2;
            int o = (ct >> 1) * 32 + 2 * (ln & 15) + (ct & 1);   // interleave-2
            int k = ks * 32 + (ln >> 4) * 8 + j;
            w2fh[i] = f2bf(w2[o * 128 + k]);
        }
        #pragma unroll
        for (int s = 0; s < 4; ++s) {
            int i = tid + s * 32768;
            int j = i & 7, ln = (i >> 3) & 63, rest = i >> 9;
            int ks = rest & 7, ct = rest >> 3;
            int o = (ct >> 2) * 64 + 4 * (ln & 15) + (ct & 3);   // interleave-4
            int c = 256 + ks * 32 + (ln >> 4) * 8 + j;
            w3fh[i] = f2bf(w3[o * 512 + c]);
        }
        return;
    }

    if (B < 5056) {
        float* b4s = (float*)shm;
        float* red = (float*)(shm + 2048);
        b4s[t] = b4[t];
        b4s[t + 256] = b4[t + 256];
        __syncthreads();
        int q0 = (B - 4992) * 8;
        for (int i = 0; i < 8; ++i) {
            int q = q0 + i;
            float part = mw2[(size_t)q * 512 + t] * b4s[t]
                       + mw2[(size_t)q * 512 + 256 + t] * b4s[256 + t];
            #pragma unroll
            for (int off = 32; off > 0; off >>= 1) part += __shfl_down(part, off);
            if (lane == 0) red[w] = part;
            __syncthreads();
            if (t == 0) bb[q] = mb2[q] + red[0] + red[1] + red[2] + red[3];
            __syncthreads();
        }
        return;
    }

    if (B < 5120) {
        float* mb1s = (float*)shm;
        float* red = (float*)(shm + 1024);
        mb1s[t] = mb1[t];
        __syncthreads();
        int o0 = (B - 5056) * 8;
        for (int i = 0; i < 8; ++i) {
            int o = o0 + i;
            float part = w3[(size_t)o * 512 + t] * mb1s[t];
            #pragma unroll
            for (int off = 32; off > 0; off >>= 1) part += __shfl_down(part, off);
            if (lane == 0) red[w] = part;
            __syncthreads();
            if (t == 0) bc3[o] = b3[o] + red[0] + red[1] + red[2] + red[3];
            __syncthreads();
        }
        return;
    }

    if (B < 5122) {
        int c = (B - 5120) * 256 + t;
        float acc = 0.f;
        for (int o = 0; o < 512; ++o) acc += sw2[o] * w4[o * 512 + c];
        u[c] = acc;
        return;
    }

    // scales + shb1 + w1 frags + ub
    if (t < 128) {
        float s = g1[t] * rsqrtf(v1[t] + EPSV);
        float sh = be1[t] - m1[t] * s;
        sc1[t] = s;
        shb1[t] = b1[t] * s + sh;
    }
    {
        float s = g2[t] * rsqrtf(v2[t] + EPSV);
        sc2[t] = s; sh2[t] = be2[t] - m2[t] * s;
        s = g2[t + 256] * rsqrtf(v2[t + 256] + EPSV);
        sc2[t + 256] = s; sh2[t + 256] = be2[t + 256] - m2[t + 256] * s;
    }
    #pragma unroll
    for (int s = 0; s < 16; ++s) {
        int i = t + s * 256;
        int j = i & 7, ln = (i >> 3) & 63, ct = i >> 9;
        int o = ct * 16 + (ln & 15);
        int k = (ln >> 4) * 8 + j;
        w1fh[i] = (k < 10) ? f2bf(w1[o * 10 + k]) : (short)0;
    }
    if (t < 64) {
        float part = 0.f;
        #pragma unroll
        for (int i = 0; i < 8; ++i) part += sw2[t * 8 + i] * b4[t * 8 + i];
        #pragma unroll
        for (int off = 32; off > 0; off >>= 1) part += __shfl_down(part, off);
        if (t == 0) ub[0] = sb2[0] + part;
    }
}

// ---------------- fused per-group MLP (4 groups/block, 512 threads) ----------
__global__ __launch_bounds__(512) void mlp_kernel(
    const float* __restrict__ xyz, const int* __restrict__ cidx,
    const int* __restrict__ knn_idx,
    const short* __restrict__ w1fh,
    const float* __restrict__ sc1, const float* __restrict__ shb1,
    const short* __restrict__ w2fh,
    const float* __restrict__ b2,
    const float* __restrict__ sw1, const float* __restrict__ sb1,
    const short* __restrict__ Pfh, const float* __restrict__ bc3,
    const short* __restrict__ w3fh,
    const float* __restrict__ sc2, const float* __restrict__ sh2,
    const float* __restrict__ u, const float* __restrict__ ubp,
    short* __restrict__ yh)
{
    __shared__ __align__(16) char smem[70656];
    short* x1 = (short*)smem;                    // [128][128] bf16 swizzled
    short* x2 = (short*)smem;                    // [128][256] bf16 swizzled (overlays x1)
    short* feat = (short*)(smem + 32768);        // [128][40]: h c0-15, l c16-31
    short* poolA = (short*)(smem + 65536);       // [8][256] bf16 swizzled, 4KB
    float* scs = (float*)(smem + 69632);         // [128]
    float* sms = (float*)(smem + 70144);         // [128]

    int gb = blockIdx.x * 4;
    int bq = gb >> 9;
    int t = threadIdx.x;
    int lane = t & 63, wv = t >> 6, q = lane >> 4, r = lane & 15;
    const float* xb = xyz + (size_t)bq * 8192 * 3;

    // P1: feat gather -> feat [128][40]
    if (t < 128) {
        int gg = t >> 5;
        int ci = cidx[gb + gg];
        float cxx = xb[ci * 3 + 0], cyy = xb[ci * 3 + 1], czz = xb[ci * 3 + 2];
        int n = knn_idx[(gb + gg) * 32 + (t & 31)];
        float nx = xb[n * 3 + 0], ny = xb[n * 3 + 1], nz = xb[n * 3 + 2];
        float rx = cxx - nx, ry = cyy - ny, rz = czz - nz;
        float rd = sqrtf(rx * rx + ry * ry + rz * rz);
        float f[10];
        f[0] = rd; f[1] = rx; f[2] = ry; f[3] = rz;
        f[4] = cxx; f[5] = cyy; f[6] = czz;
        f[7] = nx; f[8] = ny; f[9] = nz;
        unsigned* fr = (unsigned*)(feat + t * 40);
        short h0, l0, h1, l1;
        #pragma unroll
        for (int c = 0; c < 10; c += 2) {
            bsplit(f[c], h0, l0);
            bsplit(f[c + 1], h1, l1);
            fr[c >> 1] = pack2(h0, h1);
            fr[8 + (c >> 1)] = pack2(l0, l1);
        }
        fr[5] = 0; fr[6] = 0; fr[7] = 0;
        fr[13] = 0; fr[14] = 0; fr[15] = 0;
    }
    if (t < 128) scs[t] = sb1[0];
    __syncthreads();

    // P2: conv1 via MFMA: M=128, N=128 (wave: 1 ct), K=32 (10 real)
    {
        f32x4 acc1[8];
        #pragma unroll
        for (int rt = 0; rt < 8; ++rt) acc1[rt] = (f32x4){0.f, 0.f, 0.f, 0.f};
        bf16x8 bw = *(const bf16x8*)(w1fh + ((size_t)wv * 64 + lane) * 8);
        bf16x8 zerov = (bf16x8){0, 0, 0, 0, 0, 0, 0, 0};
        #pragma unroll
        for (int rt = 0; rt < 8; ++rt) {
            int row = rt * 16 + r;
            bf16x8 ah = zerov, al = zerov;
            if (q < 2) {
                ah = *(const bf16x8*)(feat + row * 40 + q * 8);
                al = *(const bf16x8*)(feat + row * 40 + 16 + q * 8);
            }
            acc1[rt] = MFMA16(al, bw, acc1[rt]);
            acc1[rt] = MFMA16(ah, bw, acc1[rt]);
        }
        int o = wv * 16 + r;
        float s1v = sc1[o], sbv = shb1[o];
        #pragma unroll
        for (int rt = 0; rt < 8; ++rt)
            #pragma unroll
            for (int j = 0; j < 4; ++j) {
                int row = rt * 16 + q * 4 + j;
                float vv = fmaxf(acc1[rt][j] * s1v + sbv, 0.f);
                x1[row * 128 + (o ^ ((row & 7) << 3))] = f2bf(vv);
            }
    }
    __syncthreads();

    // P3: conv2 via MFMA (hi weights, interleave-2): ch = wv*32 + 2r + ctl
    int ch2 = wv * 32 + 2 * r;   // even base channel of this lane's conv2 pair
    f32x4 acc2[8][2];
    {
        float2 b2v = *(const float2*)(b2 + ch2);
        #pragma unroll
        for (int rt = 0; rt < 8; ++rt) {
            acc2[rt][0] = (f32x4){b2v.x, b2v.x, b2v.x, b2v.x};
            acc2[rt][1] = (f32x4){b2v.y, b2v.y, b2v.y, b2v.y};
        }
    }
    #pragma unroll
    for (int ks = 0; ks < 4; ++ks) {
        bf16x8 af[8];
        #pragma unroll
        for (int rt = 0; rt < 8; ++rt) {
            int row = rt * 16 + r;
            int kk = ks * 32 + q * 8;
            af[rt] = *(const bf16x8*)(x1 + row * 128 + (kk ^ ((row & 7) << 3)));
        }
        #pragma unroll
        for (int ctl = 0; ctl < 2; ++ctl) {
            int ct = wv * 2 + ctl;
            size_t woff = ((size_t)(ct * 4 + ks) * 64 + lane) * 8;
            bf16x8 bh = *(const bf16x8*)(w2fh + woff);
            #pragma unroll
            for (int rt = 0; rt < 8; ++rt)
                acc2[rt][ctl] = MFMA16(af[rt], bh, acc2[rt][ctl]);
        }
    }
    // attn1 score partials
    {
        float2 sw1v = *(const float2*)(sw1 + ch2);
        #pragma unroll
        for (int rt = 0; rt < 8; ++rt)
            #pragma unroll
            for (int j = 0; j < 4; ++j) {
                float s = sw1v.x * acc2[rt][0][j] + sw1v.y * acc2[rt][1][j];
                s += __shfl_xor(s, 1); s += __shfl_xor(s, 2);
                s += __shfl_xor(s, 4); s += __shfl_xor(s, 8);
                if (r == 0) atomicAdd(&scs[rt * 16 + q * 4 + j], s);
            }
    }
    __syncthreads();

    // P4: wave-parallel softmax1 + packed x2 store (b32 per ch-pair)
    if (wv < 4 && lane < 32) {
        float s = scs[wv * 32 + lane];
        float mx = s;
        mx = fmaxf(mx, __shfl_xor(mx, 16));
        mx = fmaxf(mx, __shfl_xor(mx, 8));
        mx = fmaxf(mx, __shfl_xor(mx, 4));
        mx = fmaxf(mx, __shfl_xor(mx, 2));
        mx = fmaxf(mx, __shfl_xor(mx, 1));
        float e = expf(s - mx);
        float sum = e;
        sum += __shfl_xor(sum, 16);
        sum += __shfl_xor(sum, 8);
        sum += __shfl_xor(sum, 4);
        sum += __shfl_xor(sum, 2);
        sum += __shfl_xor(sum, 1);
        sms[wv * 32 + lane] = e / sum;
    }
    #pragma unroll
    for (int rt = 0; rt < 8; ++rt)
        #pragma unroll
        for (int j = 0; j < 4; ++j) {
            int row = rt * 16 + q * 4 + j;
            unsigned pw = cvtpk(acc2[rt][0][j], acc2[rt][1][j]);
            *(unsigned*)(x2 + row * 256 + (ch2 ^ ((row & 7) << 3))) = pw;
        }
    __syncthreads();

    // P5: pool1 -> poolA (hi row gg, lo row gg+4), packed pair writes
    {
        #pragma unroll
        for (int gg = 0; gg < 4; ++gg) {
            float pp[2];
            #pragma unroll
            for (int ctl = 0; ctl < 2; ++ctl) {
                float p = 0.f;
                #pragma unroll
                for (int rr = 0; rr < 2; ++rr) {
                    int rt = gg * 2 + rr;
                    #pragma unroll
                    for (int j = 0; j < 4; ++j)
                        p += sms[rt * 16 + q * 4 + j] * acc2[rt][ctl][j];
                }
                p += __shfl_xor(p, 16);
                p += __shfl_xor(p, 32);
                pp[ctl] = p;
            }
            if (q == 0) {
                unsigned hw = cvtpk(pp[0], pp[1]);
                float l0 = pp[0] - bf2f((short)(hw & 0xffff));
                float l1 = pp[1] - bf2f((short)(hw >> 16));
                unsigned lw = cvtpk(l0, l1);
                *(unsigned*)(poolA + gg * 256 + (ch2 ^ (gg << 3))) = hw;
                *(unsigned*)(poolA + (gg + 4) * 256 + (ch2 ^ ((gg + 4) << 3))) = lw;
            }
        }
        if (t < 128) scs[t] = ubp[0];
    }
    __syncthreads();

    // P6: pool@P via MFMA (A rows 0-7 = poolA hi/lo, 8-15 zero)
    // fragment (ct=wv*4+ctl, n=r) -> o = wv*64 + 4r + ctl  (matches P7 ch)
    float fgv[4][4];   // [ctl][group]
    f32x4 bc3v = *(const f32x4*)(bc3 + wv * 64 + 4 * r);
    {
        f32x4 accP[4];
        #pragma unroll
        for (int ctl = 0; ctl < 4; ++ctl) accP[ctl] = (f32x4){0.f, 0.f, 0.f, 0.f};
        #pragma unroll
        for (int ks = 0; ks < 8; ++ks) {
            int kk = ks * 32 + q * 8;
            bf16x8 pa;
            if (r < 8) pa = *(const bf16x8*)(poolA + r * 256 + (kk ^ (r << 3)));
            else pa = (bf16x8){0, 0, 0, 0, 0, 0, 0, 0};
            #pragma unroll
            for (int ctl = 0; ctl < 4; ++ctl) {
                size_t woff = ((size_t)((wv * 4 + ctl) * 8 + ks) * 64 + lane) * 8;
                bf16x8 ph = *(const bf16x8*)(Pfh + woff);
                accP[ctl] = MFMA16(pa, ph, accP[ctl]);
            }
        }
        #pragma unroll
        for (int ctl = 0; ctl < 4; ++ctl) {
            #pragma unroll
            for (int j = 0; j < 4; ++j) {
                float x = accP[ctl][j];
                x += __shfl_xor(x, 16);
                x += __shfl_xor(x, 32);
                fgv[ctl][j] = x;
            }
        }
    }

    // P7: conv3 via MFMA (hi weights, interleave-4): ch = wv*64 + 4r + ctl
    f32x4 acc3[8][4];
    #pragma unroll
    for (int rt = 0; rt < 8; ++rt) {
        int gg = rt >> 1;
        #pragma unroll
        for (int ctl = 0; ctl < 4; ++ctl) {
            float fp = fgv[ctl][gg] + bc3v[ctl];
            acc3[rt][ctl] = (f32x4){fp, fp, fp, fp};
        }
    }
    #pragma unroll
    for (int ks = 0; ks < 8; ++ks) {
        bf16x8 af[8];
        #pragma unroll
        for (int rt = 0; rt < 8; ++rt) {
            int row = rt * 16 + r;
            int kk = ks * 32 + q * 8;
            af[rt] = *(const bf16x8*)(x2 + row * 256 + (kk ^ ((row & 7) << 3)));
        }
        #pragma unroll
        for (int ctl = 0; ctl < 4; ++ctl) {
            int ct = wv * 4 + ctl;
            size_t woff = ((size_t)(ct * 8 + ks) * 64 + lane) * 8;
            bf16x8 bh = *(const bf16x8*)(w3fh + woff);
            #pragma unroll
            for (int rt = 0; rt < 8; ++rt)
                acc3[rt][ctl] = MFMA16(af[rt], bh, acc3[rt][ctl]);
        }
    }
    // BN2 + ReLU; attn2 score partials (vectorized channel loads)
    {
        f32x4 sc2v = *(const f32x4*)(sc2 + wv * 64 + 4 * r);
        f32x4 sh2v = *(const f32x4*)(sh2 + wv * 64 + 4 * r);
        f32x4 uv4  = *(const f32x4*)(u   + wv * 64 + 4 * r);
        #pragma unroll
        for (int ctl = 0; ctl < 4; ++ctl) {
            float s = sc2v[ctl], sh = sh2v[ctl];
            #pragma unroll
            for (int rt = 0; rt < 8; ++rt)
                #pragma unroll
                for (int j = 0; j < 4; ++j)
                    acc3[rt][ctl][j] = fmaxf(acc3[rt][ctl][j] * s + sh, 0.f);
        }
        #pragma unroll
        for (int rt = 0; rt < 8; ++rt)
            #pragma unroll
            for (int j = 0; j < 4; ++j) {
                float s = uv4[0] * acc3[rt][0][j] + uv4[1] * acc3[rt][1][j]
                        + uv4[2] * acc3[rt][2][j] + uv4[3] * acc3[rt][3][j];
                s += __shfl_xor(s, 1); s += __shfl_xor(s, 2);
                s += __shfl_xor(s, 4); s += __shfl_xor(s, 8);
                if (r == 0) atomicAdd(&scs[rt * 16 + q * 4 + j], s);
            }
    }
    __syncthreads();

    // P8: wave-parallel softmax2
    if (wv < 4 && lane < 32) {
        float s = scs[wv * 32 + lane];
        float mx = s;
        mx = fmaxf(mx, __shfl_xor(mx, 16));
        mx = fmaxf(mx, __shfl_xor(mx, 8));
        mx = fmaxf(mx, __shfl_xor(mx, 4));
        mx = fmaxf(mx, __shfl_xor(mx, 2));
        mx = fmaxf(mx, __shfl_xor(mx, 1));
        float e = expf(s - mx);
        float sum = e;
        sum += __shfl_xor(sum, 16);
        sum += __shfl_xor(sum, 8);
        sum += __shfl_xor(sum, 4);
        sum += __shfl_xor(sum, 2);
        sum += __shfl_xor(sum, 1);
        sms[wv * 32 + lane] = e / sum;
    }
    __syncthreads();

    // P9: y[g][ch] -> global bf16 (4 adjacent ch per lane -> 8B store)
    {
        #pragma unroll
        for (int gg = 0; gg < 4; ++gg) {
            float p4v[4];
            #pragma unroll
            for (int ctl = 0; ctl < 4; ++ctl) {
                float p = 0.f;
                #pragma unroll
                for (int rr = 0; rr < 2; ++rr) {
                    int rt = gg * 2 + rr;
                    #pragma unroll
                    for (int j = 0; j < 4; ++j)
                        p += sms[rt * 16 + q * 4 + j] * acc3[rt][ctl][j];
                }
                p += __shfl_xor(p, 16);
                p += __shfl_xor(p, 32);
                p4v[ctl] = p;
            }
            if (q == 0) {
                int grow = gb + gg;
                uint2 pk;
                pk.x = cvtpk(p4v[0], p4v[1]);
                pk.y = cvtpk(p4v[2], p4v[3]);
                *(uint2*)(yh + (size_t)grow * 512 + wv * 64 + 4 * r) = pk;
            }
        }
    }
}

// ---------------- fg2 GEMM: out = bb + y @ MT (hi-only) ----------------------
__global__ __launch_bounds__(256) void fg2_kernel(
    const short* __restrict__ yh,
    const short* __restrict__ MTfh,
    const float* __restrict__ bb, float* __restrict__ out_fg2)
{
    int gbase = blockIdx.x * 16;
    int t = threadIdx.x;
    int lane = t & 63, wv = t >> 6, q = lane >> 4, r = lane & 15;
    f32x4 acc[8];
    #pragma unroll
    for (int ctl = 0; ctl < 8; ++ctl) {
        float bv = bb[(wv * 8 + ctl) * 16 + r];
        acc[ctl] = (f32x4){bv, bv, bv, bv};
    }
    #pragma unroll
    for (int ks = 0; ks < 16; ++ks) {
        bf16x8 af = *(const bf16x8*)(yh + (size_t)(gbase + r) * 512 + ks * 32 + q * 8);
        #pragma unroll
        for (int ctl = 0; ctl < 8; ++ctl) {
            int ct = wv * 8 + ctl;
            size_t woff = ((size_t)(ct * 16 + ks) * 64 + lane) * 8;
            bf16x8 bh = *(const bf16x8*)(MTfh + woff);
            acc[ctl] = MFMA16(af, bh, acc[ctl]);
        }
    }
    #pragma unroll
    for (int ctl = 0; ctl < 8; ++ctl) {
        int ch = (wv * 8 + ctl) * 16 + r;
        #pragma unroll
        for (int j = 0; j < 4; ++j) {
            int grow = gbase + q * 4 + j;
            out_fg2[(size_t)grow * 512 + ch] = acc[ctl][j];
        }
    }
}

extern "C" void kernel_launch(void* const* d_in, const int* in_sizes, int n_in,
                              void* d_out, int out_size, void* d_ws, size_t ws_size,
                              hipStream_t stream) {
    const float* xyz  = (const float*)d_in[0];
    const int*   cidx = (const int*)d_in[1];
    const float* w1   = (const float*)d_in[2];
    const float* b1   = (const float*)d_in[3];
    const float* g1   = (const float*)d_in[4];
    const float* be1  = (const float*)d_in[5];
    const float* m1   = (const float*)d_in[6];
    const float* v1   = (const float*)d_in[7];
    const float* w2   = (const float*)d_in[8];
    const float* b2   = (const float*)d_in[9];
    const float* sw1  = (const float*)d_in[10];
    const float* sb1  = (const float*)d_in[11];
    const float* mw1  = (const float*)d_in[12];
    const float* mb1  = (const float*)d_in[13];
    const float* w3   = (const float*)d_in[14];
    const float* b3   = (const float*)d_in[15];
    const float* g2   = (const float*)d_in[16];
    const float* be2  = (const float*)d_in[17];
    const float* m2   = (const float*)d_in[18];
    const float* v2   = (const float*)d_in[19];
    const float* w4   = (const float*)d_in[20];
    const float* b4   = (const float*)d_in[21];
    const float* sw2  = (const float*)d_in[22];
    const float* sb2  = (const float*)d_in[23];
    const float* mw2  = (const float*)d_in[24];
    const float* mb2  = (const float*)d_in[25];

    float* out = (float*)d_out;
    char* ws = (char*)d_ws;
    int*   knn_idx = (int*)(ws + 0);             // 524288
    short* w2fh = (short*)(ws + 524288);         // 65536
    short* w3fh = (short*)(ws + 655360);         // 262144
    short* Pfh  = (short*)(ws + 1179648);        // 262144
    short* w1fh = (short*)(ws + 1441792);        // 8192
    float* bc3  = (float*)(ws + 1703936);        // 2048
    float* sc1  = (float*)(ws + 1705984);        // 512
    float* shb1 = (float*)(ws + 1706496);        // 512
    float* sc2  = (float*)(ws + 1707008);        // 2048
    float* sh2  = (float*)(ws + 1709056);        // 2048
    float* u    = (float*)(ws + 1711104);        // 2048
    float* bb   = (float*)(ws + 1713152);        // 2048
    float* ub   = (float*)(ws + 1715200);        // 256 (pad)
    short* MTfh = (short*)(ws + 1715456);        // 524288
    short* yh   = (short*)(ws + 2764032);        // 4194304

    prep_knn<<<5123, 256, 0, stream>>>(xyz, cidx, knn_idx, out,
                                       w1, b1, w2, w3, mw1, mw2, w4, b4, sw2, sb2,
                                       mb2, mb1, b3,
                                       g1, be1, m1, v1, g2, be2, m2, v2,
                                       w1fh, w2fh, w3fh, Pfh, MTfh,
                                       sc1, shb1, sc2, sh2, u, bb, ub, bc3);
    mlp_kernel<<<1024, 512, 0, stream>>>(xyz, cidx, knn_idx,
                                         w1fh, sc1, shb1, w2fh, b2,
                                         sw1, sb1, Pfh, bc3, w3fh,
                                         sc2, sh2, u, ub, yh);
    fg2_kernel<<<256, 256, 0, stream>>>(yh, MTfh, bb, out + 12288);
}